// Round 11
// baseline (589.265 us; speedup 1.0000x reference)
//
#include <hip/hip_runtime.h>
#include <math.h>

typedef __attribute__((ext_vector_type(8))) short bf16x8;
typedef __attribute__((ext_vector_type(4))) float f32x4;
typedef __attribute__((ext_vector_type(4))) unsigned short us4;
typedef __attribute__((ext_vector_type(8))) unsigned short us8;

static constexpr int kN  = 50000;
static constexpr int kE  = 800000;
static constexpr int kNBUK = 98;     // ceil(50000/512), bucket = dst>>9
static constexpr int kCAP  = 9216;   // per-bucket payload cap (mean 8163 + 11.6 sigma)

__device__ __forceinline__ float b2f(unsigned short u) {
  union { unsigned u; float f; } x; x.u = ((unsigned)u) << 16; return x.f;
}
__device__ __forceinline__ unsigned short f2b(float f) {
  union { float f; unsigned u; } x; x.f = f;
  unsigned u = x.u;
  unsigned r = (u + 0x7fffu + ((u >> 16) & 1u)) >> 16;
  return (unsigned short)r;
}

// ---------------- fused prep: Wt_a, Wt_b (bf16 [256][256]), W1T (bf16 [128][256])
__global__ __launch_bounds__(256)
void k_prep(const float* __restrict__ Wa, const float* __restrict__ Wb,
            const float* __restrict__ W1,
            unsigned short* __restrict__ wta, unsigned short* __restrict__ wtb,
            unsigned short* __restrict__ w1t) {
  int b = blockIdx.x, t = threadIdx.x;
  if (b < 256) {
    int i = b * 256 + t, j = i >> 8, k = i & 255;
    wta[j * 256 + k] = f2b(Wa[k * 256 + j]);
  } else if (b < 512) {
    int i = (b - 256) * 256 + t, j = i >> 8, k = i & 255;
    wtb[j * 256 + k] = f2b(Wb[k * 256 + j]);
  } else {
    int i = (b - 512) * 256 + t, j = i >> 8, k = i & 255;  // j<128
    w1t[j * 256 + k] = f2b(W1[k * 128 + j]);
  }
}

// ---------------- feat = h @ W + fused el/er (r10 passing version) ---------
__global__ __launch_bounds__(512, 6)
void k_gemm(const float* __restrict__ h,
            const unsigned short* __restrict__ wta,
            const unsigned short* __restrict__ wtb,
            const float* __restrict__ ala, const float* __restrict__ ara,
            const float* __restrict__ alb, const float* __restrict__ arb,
            unsigned short* __restrict__ fa, unsigned short* __restrict__ fb,
            float* __restrict__ ela, float* __restrict__ era,
            float* __restrict__ elb, float* __restrict__ erb) {
  __shared__ us8 la[64 * 8];                   // 8KB
  __shared__ us8 lbb[256 * 8];                 // 32KB
  const int z = blockIdx.y;
  const unsigned short* wt = z ? wtb : wta;
  unsigned short* f = z ? fb : fa;
  const float* al = z ? alb : ala;
  const float* ar = z ? arb : ara;
  float* el = z ? elb : ela;
  float* er = z ? erb : era;
  const int m0 = blockIdx.x * 64;
  const int t = threadIdx.x;
  const int lane = t & 63;
  const int wave = t >> 6;                     // 0..7 == head
  const int col = lane & 15;
  const int quad = lane >> 4;
  const int nw = wave * 32;                    // this wave's 32 cols
  f32x4 acc[4][2];
#pragma unroll
  for (int i = 0; i < 4; ++i)
#pragma unroll
    for (int j = 0; j < 2; ++j) acc[i][j] = (f32x4){0.f, 0.f, 0.f, 0.f};

  for (int ks = 0; ks < 4; ++ks) {
    const int k0 = ks * 64;
    __syncthreads();
    // stage A: 64 rows x 64 k, fp32 -> bf16. 1024 8B-units, 2 iters.
#pragma unroll
    for (int i = 0; i < 2; ++i) {
      int idx = i * 512 + t;
      int r = idx >> 4, g = (idx >> 1) & 7, half = idx & 1;
      int gr = m0 + r;
      f32x4 v = {0.f, 0.f, 0.f, 0.f};
      if (gr < kN) v = *(const f32x4*)(h + (size_t)gr * 256 + k0 + g * 8 + half * 4);
      us4 o;
      o.x = f2b(v.x); o.y = f2b(v.y); o.z = f2b(v.z); o.w = f2b(v.w);
      *(us4*)((unsigned short*)&la[r * 8 + (g ^ (r & 7))] + half * 4) = o;
    }
    // stage B: 256 rows x 64 k bf16. 2048 16B-units, 4 iters.
#pragma unroll
    for (int i = 0; i < 4; ++i) {
      int idx = i * 512 + t;
      int r = idx >> 3, g = idx & 7;
      lbb[r * 8 + (g ^ (r & 7))] = *(const us8*)(wt + r * 256 + k0 + g * 8);
    }
    __syncthreads();
#pragma unroll
    for (int k32 = 0; k32 < 64; k32 += 32) {
      const int cg = (k32 >> 3) + quad;
      bf16x8 af[4], bf[2];
#pragma unroll
      for (int s = 0; s < 4; ++s) {
        int arow = s * 16 + col;
        af[s] = (bf16x8)la[arow * 8 + (cg ^ (arow & 7))];
      }
#pragma unroll
      for (int j = 0; j < 2; ++j) {
        int brow = nw + j * 16 + col;
        bf[j] = (bf16x8)lbb[brow * 8 + (cg ^ (brow & 7))];
      }
#pragma unroll
      for (int i = 0; i < 4; ++i)
#pragma unroll
        for (int j = 0; j < 2; ++j)
          acc[i][j] = __builtin_amdgcn_mfma_f32_16x16x32_bf16(af[i], bf[j],
                                                              acc[i][j], 0, 0, 0);
    }
  }
  // epilogue 1: feat store (C row = quad*4+reg, col = lane&15)
#pragma unroll
  for (int i = 0; i < 4; ++i) {
#pragma unroll
    for (int r = 0; r < 4; ++r) {
      int row = m0 + i * 16 + quad * 4 + r;
      if (row < kN) {
#pragma unroll
        for (int j = 0; j < 2; ++j)
          f[(size_t)row * 256 + nw + j * 16 + col] = f2b(acc[i][j][r]);
      }
    }
  }
  // epilogue 2: el/er for this wave's single head (cols nw..nw+31)
  float alv[2], arv[2];
#pragma unroll
  for (int j = 0; j < 2; ++j) {
    alv[j] = al[nw + j * 16 + col];
    arv[j] = ar[nw + j * 16 + col];
  }
#pragma unroll
  for (int i = 0; i < 4; ++i) {
#pragma unroll
    for (int r = 0; r < 4; ++r) {
      float pl = acc[i][0][r] * alv[0] + acc[i][1][r] * alv[1];
      float pr = acc[i][0][r] * arv[0] + acc[i][1][r] * arv[1];
#pragma unroll
      for (int off = 1; off < 16; off <<= 1) {
        pl += __shfl_xor(pl, off);
        pr += __shfl_xor(pr, off);
      }
      int row = m0 + i * 16 + quad * 4 + r;
      if (col == 0 && row < kN) {
        el[row * 8 + wave] = pl;
        er[row * 8 + wave] = pr;
      }
    }
  }
}

// ---------------- CSR build via radix partition ----------------------------
__global__ __launch_bounds__(256)
void k_part(const int* __restrict__ sa, const int* __restrict__ da,
            const int* __restrict__ sb, const int* __restrict__ db,
            int* __restrict__ cnt, unsigned* __restrict__ pay) {
  int y = blockIdx.y;
  const int* s = y ? sb : sa;
  const int* d = y ? db : da;
  unsigned* p = pay + (size_t)y * kNBUK * kCAP;
  int* cn = cnt + y * kNBUK;
  __shared__ unsigned stash[6400];              // 25.6KB
  __shared__ int h[kNBUK];
  int t = threadIdx.x;
  if (t < kNBUK) h[t] = 0;
  __syncthreads();
  int e0 = blockIdx.x * 6400;
#pragma unroll 5
  for (int it = 0; it < 25; ++it) {
    int e = e0 + it * 256 + t;
    int sv = s[e], dv = d[e];
    int b = dv >> 9;
    stash[it * 256 + t] = (unsigned)sv | ((unsigned)(dv & 511) << 16) |
                          ((unsigned)b << 25);
    atomicAdd(&h[b], 1);
  }
  __syncthreads();
  if (t < kNBUK) h[t] = atomicAdd(&cn[t], h[t]);  // h becomes block's cursor
  __syncthreads();
#pragma unroll 5
  for (int it = 0; it < 25; ++it) {
    unsigned w = stash[it * 256 + t];
    int b = w >> 25;
    int slot = atomicAdd(&h[b], 1);
    p[b * kCAP + slot] = w & 0x1FFFFFFu;
  }
}

// k_bscan: exclusive scan of 2x98 bucket counts -> global es/rp bases.
__global__ __launch_bounds__(256)
void k_bscan(const int* __restrict__ cnt, int* __restrict__ bbase,
             int* __restrict__ rpa, int* __restrict__ rpb) {
  __shared__ int buf[2][128];
  int t = threadIdx.x;
  int y = t >> 7, i = t & 127;
  int x = (i < kNBUK) ? cnt[y * kNBUK + i] : 0;
  buf[y][i] = x;
  __syncthreads();
  for (int off = 1; off < 128; off <<= 1) {
    int v = (i >= off) ? buf[y][i - off] : 0;
    __syncthreads();
    buf[y][i] += v;
    __syncthreads();
  }
  if (i < kNBUK) bbase[y * kNBUK + i] = buf[y][i] - x;
  if (t == 0) { rpa[kN] = kE; rpb[kN] = kE; }
}

// k_bucket: one block per (bucket, graph). LDS histogram + pair scan ->
// writes rp segment AND scatters es via LDS cursor atomics.
__global__ __launch_bounds__(256)
void k_bucket(const int* __restrict__ cnt, const int* __restrict__ bbase,
              const unsigned* __restrict__ pay,
              int* __restrict__ rpa, int* __restrict__ rpb,
              int* __restrict__ esa, int* __restrict__ esb) {
  int b = blockIdx.x, y = blockIdx.y;
  int* rp = y ? rpb : rpa;
  int* es = y ? esb : esa;
  const unsigned* p = pay + ((size_t)y * kNBUK + b) * kCAP;
  int c = cnt[y * kNBUK + b];
  int base = bbase[y * kNBUK + b];
  __shared__ unsigned pl[kCAP];                 // 36.9KB
  __shared__ int h[512];
  __shared__ int buf[256];
  int t = threadIdx.x;
  h[t] = 0; h[t + 256] = 0;
  __syncthreads();
  for (int i = t; i < c; i += 256) {
    unsigned w = p[i];
    pl[i] = w;
    atomicAdd(&h[(w >> 16) & 511], 1);
  }
  __syncthreads();
  int a = h[2 * t], b1 = h[2 * t + 1];
  int s2 = a + b1;
  buf[t] = s2;
  __syncthreads();
  for (int off = 1; off < 256; off <<= 1) {
    int v = (t >= off) ? buf[t - off] : 0;
    __syncthreads();
    buf[t] += v;
    __syncthreads();
  }
  int ex = buf[t] - s2;                         // exclusive pair base
  int g0 = b * 512 + 2 * t;
  if (g0 < kN) rp[g0] = base + ex;
  if (g0 + 1 < kN) rp[g0 + 1] = base + ex + a;
  h[2 * t] = ex;                                // h becomes local cursors
  h[2 * t + 1] = ex + a;
  __syncthreads();
  for (int i = t; i < c; i += 256) {
    unsigned w = pl[i];
    int slot = atomicAdd(&h[(w >> 16) & 511], 1);
    es[base + slot] = (int)(w & 0xFFFFu);
  }
}

// ---------------- GAT aggregate (round-3 proven structure, per-graph) ------
__global__ __launch_bounds__(256)
void k_agg(const int* __restrict__ rp, const int* __restrict__ es,
           const float* __restrict__ el, const float* __restrict__ er,
           const unsigned short* __restrict__ feat,
           const float* __restrict__ bias,
           float* __restrict__ za, unsigned short* __restrict__ zb,
           int y) {
  __shared__ float wls[4][512];                // 64 edges x 8 heads per wave
  __shared__ int sls[4][64];
  int nb = blockIdx.x;
  int lane = threadIdx.x & 63;
  int wave = threadIdx.x >> 6;
  int n = nb * 4 + wave;
  int hh = lane >> 3;                          // phase1 edge-slot
  int h = lane & 7;                            // phase1 head
  int half = lane >> 5;                        // phase2: which edge of pair
  int l5 = lane & 31;
  int h2 = l5 >> 2;                            // phase2 head (dims l5*8..+7)
  unsigned idx16 = (unsigned)l5 * 16u;         // byte offset in feat row
  float erh = er[n * 8 + h];
  int e0 = rp[n], e1 = rp[n + 1];
  float dsum = 0.f;
  float a0 = 0.f, a1 = 0.f, a2 = 0.f, a3 = 0.f;
  float a4 = 0.f, a5 = 0.f, a6 = 0.f, a7 = 0.f;

  for (int cb = e0; cb < e1; cb += 64) {
    int cnt = e1 - cb;
    if (cnt > 64) cnt = 64;
    // phase 1: weights -> LDS, 8 edges/iter, no lane redundancy
    for (int it = 0; it * 8 < cnt; ++it) {
      int j = it * 8 + hh;
      if (j < cnt) {
        int s = es[cb + j];
        float ev = *(const float*)((const char*)el + ((unsigned)s << 5) +
                                   ((unsigned)h << 2)) + erh;
        ev = fmaxf(ev, 0.2f * ev);             // LeakyReLU(0.2)
        float w = __expf(ev);
        wls[wave][it * 64 + lane] = w;         // == [j*8 + h]
        if (h == 0) sls[wave][j] = s;
        dsum += w;
      }
    }
    // phase 2: 2 edges/instr, 16B/lane (same-wave LDS dep, no barrier)
    int j = 0;
    for (; j + 7 < cnt; j += 8) {
#pragma unroll
      for (int p = 0; p < 4; ++p) {
        int jj = j + 2 * p + half;
        int s = sls[wave][jj];
        float w = wls[wave][jj * 8 + h2];
        us8 fv = *(const us8*)((const char*)feat + (((unsigned)s << 9) + idx16));
        a0 += w * b2f(fv[0]);
        a1 += w * b2f(fv[1]);
        a2 += w * b2f(fv[2]);
        a3 += w * b2f(fv[3]);
        a4 += w * b2f(fv[4]);
        a5 += w * b2f(fv[5]);
        a6 += w * b2f(fv[6]);
        a7 += w * b2f(fv[7]);
      }
    }
    if (j < cnt) {
#pragma unroll
      for (int p = 0; p < 4; ++p) {
        int jj = j + 2 * p + half;
        bool v = jj < cnt;
        int jc = v ? jj : j;
        int s = sls[wave][jc];
        float w = v ? wls[wave][jc * 8 + h2] : 0.f;
        us8 fv = *(const us8*)((const char*)feat + (((unsigned)s << 9) + idx16));
        a0 += w * b2f(fv[0]);
        a1 += w * b2f(fv[1]);
        a2 += w * b2f(fv[2]);
        a3 += w * b2f(fv[3]);
        a4 += w * b2f(fv[4]);
        a5 += w * b2f(fv[5]);
        a6 += w * b2f(fv[6]);
        a7 += w * b2f(fv[7]);
      }
    }
  }
  // combine halves (each half holds alternating edges' partials)
  a0 += __shfl_xor(a0, 32); a1 += __shfl_xor(a1, 32);
  a2 += __shfl_xor(a2, 32); a3 += __shfl_xor(a3, 32);
  a4 += __shfl_xor(a4, 32); a5 += __shfl_xor(a5, 32);
  a6 += __shfl_xor(a6, 32); a7 += __shfl_xor(a7, 32);
  // denom: reduce over edge-slot bits; lane i holds head i&7 total
  dsum += __shfl_xor(dsum, 8);
  dsum += __shfl_xor(dsum, 16);
  dsum += __shfl_xor(dsum, 32);
  float dh = __shfl(dsum, h2);                 // this lane's head total
  float inv = __builtin_amdgcn_rcpf(dh > 0.f ? dh : 1.f);
  f32x4 blo = *(const f32x4*)(bias + l5 * 8);
  f32x4 bhi = *(const f32x4*)(bias + l5 * 8 + 4);
  float r0 = a0 * inv + blo.x;
  float r1 = a1 * inv + blo.y;
  float r2 = a2 * inv + blo.z;
  float r3 = a3 * inv + blo.w;
  float r4 = a4 * inv + bhi.x;
  float r5 = a5 * inv + bhi.y;
  float r6 = a6 * inv + bhi.z;
  float r7 = a7 * inv + bhi.w;
  r0 = r0 > 0.f ? r0 : __expf(r0) - 1.f;       // ELU (no libm)
  r1 = r1 > 0.f ? r1 : __expf(r1) - 1.f;
  r2 = r2 > 0.f ? r2 : __expf(r2) - 1.f;
  r3 = r3 > 0.f ? r3 : __expf(r3) - 1.f;
  r4 = r4 > 0.f ? r4 : __expf(r4) - 1.f;
  r5 = r5 > 0.f ? r5 : __expf(r5) - 1.f;
  r6 = r6 > 0.f ? r6 : __expf(r6) - 1.f;
  r7 = r7 > 0.f ? r7 : __expf(r7) - 1.f;
  f32x4 lo = {r0, r1, r2, r3};
  f32x4 hi = {r4, r5, r6, r7};
  f32x4 ov = half ? hi : lo;
  if (y == 0) {
    *(f32x4*)((char*)za + (size_t)n * 1024 + l5 * 32 + half * 16) = ov;
  } else {
    us4 o;
    o.x = f2b(ov.x); o.y = f2b(ov.y); o.z = f2b(ov.z); o.w = f2b(ov.w);
    *(us4*)((char*)zb + (size_t)n * 512 + l5 * 16 + half * 8) = o;
  }
}

// ---------------- semantic scores via MFMA, W1 slices in registers ---------
// r10 diagnosis: 188 VGPR + 64KB LDS -> 8.5% occupancy, 524K bank conflicts,
// 78us for a ~16us-roofline kernel. tanh-sum is separable over hidden-j:
// wave w owns j in [w*32,w*32+32) -> its W1T slice (16KB) lives in 64 VGPRs
// loaded once per block. LDS shrinks to one 8KB A-tile staged cooperatively
// (f32->bf16 conversion once per block, k_gemm's proven conflict-free
// swizzle). ~100 VGPR + 8KB LDS -> 4 blocks/CU, ~50% occupancy. Grid 2048.
__global__ __launch_bounds__(256, 4)
void k_sem(const float* __restrict__ za,
           const unsigned short* __restrict__ zb,
           const unsigned short* __restrict__ w1t,
           const float* __restrict__ b1,
           const float* __restrict__ W2,
           float* __restrict__ wacc) {
  __shared__ us8 al[512];                       // 16 rows x 32 chunks, 8KB
  int t = threadIdx.x;
  int lane = t & 63, wave = t >> 6;
  int col = lane & 15, quad = lane >> 4;
  // register-held W1T slice: this wave covers j in [wave*32, wave*32+32)
  bf16x8 breg[2][8];
  float b1v[2], w2v[2];
#pragma unroll
  for (int tl = 0; tl < 2; ++tl) {
    int j = (wave * 2 + tl) * 16 + col;
    b1v[tl] = b1[j];
    w2v[tl] = W2[j];
#pragma unroll
    for (int ks = 0; ks < 8; ++ks)
      breg[tl][ks] = *(const bf16x8*)(w1t + j * 256 + (ks * 4 + quad) * 8);
  }
  float sa = 0.f, sb = 0.f;
  for (int gt = blockIdx.x; gt < 6250; gt += gridDim.x) {
    __syncthreads();                            // al readers from prev iter done
    // stage A tile (16 rows x 256 k) -> LDS, swizzled like k_gemm's la
    if (gt < 3125) {
      const float* src = za + (size_t)gt * 4096;
#pragma unroll
      for (int i = 0; i < 2; ++i) {
        int idx = i * 256 + t;
        int r = idx >> 5, c = idx & 31;
        f32x4 v0 = *(const f32x4*)(src + r * 256 + c * 8);
        f32x4 v1 = *(const f32x4*)(src + r * 256 + c * 8 + 4);
        us8 o;
        o[0] = (unsigned short)f2b(v0.x); o[1] = (unsigned short)f2b(v0.y);
        o[2] = (unsigned short)f2b(v0.z); o[3] = (unsigned short)f2b(v0.w);
        o[4] = (unsigned short)f2b(v1.x); o[5] = (unsigned short)f2b(v1.y);
        o[6] = (unsigned short)f2b(v1.z); o[7] = (unsigned short)f2b(v1.w);
        al[r * 32 + (c & 24) + ((c & 7) ^ (r & 7))] = o;
      }
    } else {
      const unsigned short* src = zb + (size_t)(gt - 3125) * 4096;
#pragma unroll
      for (int i = 0; i < 2; ++i) {
        int idx = i * 256 + t;
        int r = idx >> 5, c = idx & 31;
        al[r * 32 + (c & 24) + ((c & 7) ^ (r & 7))] =
            *(const us8*)(src + r * 256 + c * 8);
      }
    }
    __syncthreads();
    f32x4 acc0 = {0.f, 0.f, 0.f, 0.f};
    f32x4 acc1 = {0.f, 0.f, 0.f, 0.f};
#pragma unroll
    for (int ks = 0; ks < 8; ++ks) {
      int c = ks * 4 + quad;
      bf16x8 a = (bf16x8)al[col * 32 + (c & 24) + ((c & 7) ^ (col & 7))];
      acc0 = __builtin_amdgcn_mfma_f32_16x16x32_bf16(a, breg[0][ks], acc0, 0, 0, 0);
      acc1 = __builtin_amdgcn_mfma_f32_16x16x32_bf16(a, breg[1][ks], acc1, 0, 0, 0);
    }
    float tot = 0.f;
#pragma unroll
    for (int r = 0; r < 4; ++r) {
      float x0 = acc0[r] + b1v[0];
      x0 = fminf(fmaxf(x0, -10.f), 10.f);
      float e0 = __expf(2.f * x0);
      tot += (e0 - 1.f) * __builtin_amdgcn_rcpf(e0 + 1.f) * w2v[0];
      float x1 = acc1[r] + b1v[1];
      x1 = fminf(fmaxf(x1, -10.f), 10.f);
      float e1 = __expf(2.f * x1);
      tot += (e1 - 1.f) * __builtin_amdgcn_rcpf(e1 + 1.f) * w2v[1];
    }
#pragma unroll
    for (int off = 1; off < 64; off <<= 1) tot += __shfl_xor(tot, off);
    if (gt < 3125) sa += tot; else sb += tot;
  }
  if (lane == 0) {
    if (sa != 0.f) atomicAdd(&wacc[0], sa);
    if (sb != 0.f) atomicAdd(&wacc[1], sb);
  }
}

// ---------------- beta softmax + combine (in-place over za==out) -----------
__global__ __launch_bounds__(256)
void k_combine(const float* __restrict__ za,
               const unsigned short* __restrict__ zb,
               const float* __restrict__ wacc,
               float* __restrict__ out) {
  int i = blockIdx.x * 256 + threadIdx.x;       // 3.2M groups of 4
  float wa = wacc[0] * (1.f / kN), wb = wacc[1] * (1.f / kN);
  float mx = fmaxf(wa, wb);
  float ea = __expf(wa - mx), eb = __expf(wb - mx);
  float inv = __builtin_amdgcn_rcpf(ea + eb);
  float ba = ea * inv, bb = eb * inv;
  f32x4 x = ((const f32x4*)za)[i];
  us4 yv = ((const us4*)zb)[i];
  f32x4 o;
#pragma unroll
  for (int j = 0; j < 4; ++j)
    o[j] = ba * x[j] + bb * b2f(yv[j]);
  ((f32x4*)out)[i] = o;
}

extern "C" void kernel_launch(void* const* d_in, const int* in_sizes, int n_in,
                              void* d_out, int out_size, void* d_ws, size_t ws_size,
                              hipStream_t stream) {
  const float* hin = (const float*)d_in[0];
  const int* src_a = (const int*)d_in[1];
  const int* dst_a = (const int*)d_in[2];
  const int* src_b = (const int*)d_in[3];
  const int* dst_b = (const int*)d_in[4];
  const float* W_a = (const float*)d_in[5];
  const float* al_a = (const float*)d_in[6];
  const float* ar_a = (const float*)d_in[7];
  const float* bias_a = (const float*)d_in[8];
  const float* W_b = (const float*)d_in[9];
  const float* al_b = (const float*)d_in[10];
  const float* ar_b = (const float*)d_in[11];
  const float* bias_b = (const float*)d_in[12];
  const float* sW1 = (const float*)d_in[13];
  const float* sb1 = (const float*)d_in[14];
  const float* sW2 = (const float*)d_in[15];
  float* out = (float*)d_out;

  char* wsb = (char*)d_ws;
  size_t off = 0;
  auto alloc = [&](size_t bytes) -> char* {
    char* p = wsb + off;
    off = (off + bytes + 511) & ~(size_t)511;
    return p;
  };
  // Footprint ~98 MB.
  unsigned short* feat_a = (unsigned short*)alloc((size_t)kN * 256 * 2); // 25.6MB
  unsigned short* feat_b = (unsigned short*)alloc((size_t)kN * 256 * 2); // 25.6MB
  unsigned short* z_b    = (unsigned short*)alloc((size_t)kN * 256 * 2); // 25.6MB
  float* el_a = (float*)alloc((size_t)kN * 8 * 4);
  float* er_a = (float*)alloc((size_t)kN * 8 * 4);
  float* el_b = (float*)alloc((size_t)kN * 8 * 4);
  float* er_b = (float*)alloc((size_t)kN * 8 * 4);
  unsigned short* wt_a = (unsigned short*)alloc(65536 * 2);
  unsigned short* wt_b = (unsigned short*)alloc(65536 * 2);
  unsigned short* w1t  = (unsigned short*)alloc(32768 * 2);
  int* rp_a = (int*)alloc((size_t)(kN + 1) * 4);
  int* rp_b = (int*)alloc((size_t)(kN + 1) * 4);
  int* es_a = (int*)alloc((size_t)kE * 4);
  int* es_b = (int*)alloc((size_t)kE * 4);
  unsigned* pay = (unsigned*)alloc((size_t)2 * kNBUK * kCAP * 4);  // 7.2MB
  int* cnt = (int*)alloc((size_t)2 * kNBUK * 4);
  int* bbase = (int*)alloc((size_t)2 * kNBUK * 4);
  float* wacc = (float*)alloc(2 * 4);

  hipMemsetAsync(cnt, 0, (size_t)2 * kNBUK * 4, stream);
  hipMemsetAsync(wacc, 0, 8, stream);

  k_prep<<<640, 256, 0, stream>>>(W_a, W_b, sW1, wt_a, wt_b, w1t);
  k_part<<<dim3(125, 2), 256, 0, stream>>>(src_a, dst_a, src_b, dst_b, cnt, pay);
  k_bscan<<<1, 256, 0, stream>>>(cnt, bbase, rp_a, rp_b);
  k_bucket<<<dim3(kNBUK, 2), 256, 0, stream>>>(cnt, bbase, pay,
                                               rp_a, rp_b, es_a, es_b);
  k_gemm<<<dim3(782, 2), 512, 0, stream>>>(hin, wt_a, wt_b,
                                           al_a, ar_a, al_b, ar_b,
                                           feat_a, feat_b,
                                           el_a, er_a, el_b, er_b);
  k_agg<<<12500, 256, 0, stream>>>(rp_a, es_a, el_a, er_a, feat_a, bias_a,
                                   out, z_b, 0);
  k_agg<<<12500, 256, 0, stream>>>(rp_b, es_b, el_b, er_b, feat_b, bias_b,
                                   out, z_b, 1);
  k_sem<<<2048, 256, 0, stream>>>(out, z_b, w1t, sb1, sW2, wacc);
  k_combine<<<12500, 256, 0, stream>>>(out, z_b, wacc, out);
}

// Round 12
// 530.293 us; speedup vs baseline: 1.1112x; 1.1112x over previous
//
#include <hip/hip_runtime.h>
#include <math.h>

typedef __attribute__((ext_vector_type(8))) short bf16x8;
typedef __attribute__((ext_vector_type(4))) float f32x4;
typedef __attribute__((ext_vector_type(4))) unsigned short us4;
typedef __attribute__((ext_vector_type(8))) unsigned short us8;

static constexpr int kN  = 50000;
static constexpr int kE  = 800000;
static constexpr int kNBUK = 98;     // ceil(50000/512), bucket = dst>>9
static constexpr int kCAP  = 9216;   // per-bucket payload cap (mean 8163 + 11.6 sigma)

__device__ __forceinline__ float b2f(unsigned short u) {
  union { unsigned u; float f; } x; x.u = ((unsigned)u) << 16; return x.f;
}
__device__ __forceinline__ unsigned short f2b(float f) {
  union { float f; unsigned u; } x; x.f = f;
  unsigned u = x.u;
  unsigned r = (u + 0x7fffu + ((u >> 16) & 1u)) >> 16;
  return (unsigned short)r;
}

// ---------------- fused prep: Wt_a, Wt_b (bf16 [256][256]), W1T (bf16 [128][256])
__global__ __launch_bounds__(256)
void k_prep(const float* __restrict__ Wa, const float* __restrict__ Wb,
            const float* __restrict__ W1,
            unsigned short* __restrict__ wta, unsigned short* __restrict__ wtb,
            unsigned short* __restrict__ w1t) {
  int b = blockIdx.x, t = threadIdx.x;
  if (b < 256) {
    int i = b * 256 + t, j = i >> 8, k = i & 255;
    wta[j * 256 + k] = f2b(Wa[k * 256 + j]);
  } else if (b < 512) {
    int i = (b - 256) * 256 + t, j = i >> 8, k = i & 255;
    wtb[j * 256 + k] = f2b(Wb[k * 256 + j]);
  } else {
    int i = (b - 512) * 256 + t, j = i >> 8, k = i & 255;  // j<128
    w1t[j * 256 + k] = f2b(W1[k * 128 + j]);
  }
}

// ---------------- feat = h @ W + fused el/er (r10 passing version) ---------
__global__ __launch_bounds__(512, 6)
void k_gemm(const float* __restrict__ h,
            const unsigned short* __restrict__ wta,
            const unsigned short* __restrict__ wtb,
            const float* __restrict__ ala, const float* __restrict__ ara,
            const float* __restrict__ alb, const float* __restrict__ arb,
            unsigned short* __restrict__ fa, unsigned short* __restrict__ fb,
            float* __restrict__ ela, float* __restrict__ era,
            float* __restrict__ elb, float* __restrict__ erb) {
  __shared__ us8 la[64 * 8];                   // 8KB
  __shared__ us8 lbb[256 * 8];                 // 32KB
  const int z = blockIdx.y;
  const unsigned short* wt = z ? wtb : wta;
  unsigned short* f = z ? fb : fa;
  const float* al = z ? alb : ala;
  const float* ar = z ? arb : ara;
  float* el = z ? elb : ela;
  float* er = z ? erb : era;
  const int m0 = blockIdx.x * 64;
  const int t = threadIdx.x;
  const int lane = t & 63;
  const int wave = t >> 6;                     // 0..7 == head
  const int col = lane & 15;
  const int quad = lane >> 4;
  const int nw = wave * 32;                    // this wave's 32 cols
  f32x4 acc[4][2];
#pragma unroll
  for (int i = 0; i < 4; ++i)
#pragma unroll
    for (int j = 0; j < 2; ++j) acc[i][j] = (f32x4){0.f, 0.f, 0.f, 0.f};

  for (int ks = 0; ks < 4; ++ks) {
    const int k0 = ks * 64;
    __syncthreads();
    // stage A: 64 rows x 64 k, fp32 -> bf16. 1024 8B-units, 2 iters.
#pragma unroll
    for (int i = 0; i < 2; ++i) {
      int idx = i * 512 + t;
      int r = idx >> 4, g = (idx >> 1) & 7, half = idx & 1;
      int gr = m0 + r;
      f32x4 v = {0.f, 0.f, 0.f, 0.f};
      if (gr < kN) v = *(const f32x4*)(h + (size_t)gr * 256 + k0 + g * 8 + half * 4);
      us4 o;
      o.x = f2b(v.x); o.y = f2b(v.y); o.z = f2b(v.z); o.w = f2b(v.w);
      *(us4*)((unsigned short*)&la[r * 8 + (g ^ (r & 7))] + half * 4) = o;
    }
    // stage B: 256 rows x 64 k bf16. 2048 16B-units, 4 iters.
#pragma unroll
    for (int i = 0; i < 4; ++i) {
      int idx = i * 512 + t;
      int r = idx >> 3, g = idx & 7;
      lbb[r * 8 + (g ^ (r & 7))] = *(const us8*)(wt + r * 256 + k0 + g * 8);
    }
    __syncthreads();
#pragma unroll
    for (int k32 = 0; k32 < 64; k32 += 32) {
      const int cg = (k32 >> 3) + quad;
      bf16x8 af[4], bf[2];
#pragma unroll
      for (int s = 0; s < 4; ++s) {
        int arow = s * 16 + col;
        af[s] = (bf16x8)la[arow * 8 + (cg ^ (arow & 7))];
      }
#pragma unroll
      for (int j = 0; j < 2; ++j) {
        int brow = nw + j * 16 + col;
        bf[j] = (bf16x8)lbb[brow * 8 + (cg ^ (brow & 7))];
      }
#pragma unroll
      for (int i = 0; i < 4; ++i)
#pragma unroll
        for (int j = 0; j < 2; ++j)
          acc[i][j] = __builtin_amdgcn_mfma_f32_16x16x32_bf16(af[i], bf[j],
                                                              acc[i][j], 0, 0, 0);
    }
  }
  // epilogue 1: feat store (C row = quad*4+reg, col = lane&15)
#pragma unroll
  for (int i = 0; i < 4; ++i) {
#pragma unroll
    for (int r = 0; r < 4; ++r) {
      int row = m0 + i * 16 + quad * 4 + r;
      if (row < kN) {
#pragma unroll
        for (int j = 0; j < 2; ++j)
          f[(size_t)row * 256 + nw + j * 16 + col] = f2b(acc[i][j][r]);
      }
    }
  }
  // epilogue 2: el/er for this wave's single head (cols nw..nw+31)
  float alv[2], arv[2];
#pragma unroll
  for (int j = 0; j < 2; ++j) {
    alv[j] = al[nw + j * 16 + col];
    arv[j] = ar[nw + j * 16 + col];
  }
#pragma unroll
  for (int i = 0; i < 4; ++i) {
#pragma unroll
    for (int r = 0; r < 4; ++r) {
      float pl = acc[i][0][r] * alv[0] + acc[i][1][r] * alv[1];
      float pr = acc[i][0][r] * arv[0] + acc[i][1][r] * arv[1];
#pragma unroll
      for (int off = 1; off < 16; off <<= 1) {
        pl += __shfl_xor(pl, off);
        pr += __shfl_xor(pr, off);
      }
      int row = m0 + i * 16 + quad * 4 + r;
      if (col == 0 && row < kN) {
        el[row * 8 + wave] = pl;
        er[row * 8 + wave] = pr;
      }
    }
  }
}

// ---------------- CSR build via radix partition ----------------------------
__global__ __launch_bounds__(256)
void k_part(const int* __restrict__ sa, const int* __restrict__ da,
            const int* __restrict__ sb, const int* __restrict__ db,
            int* __restrict__ cnt, unsigned* __restrict__ pay) {
  int y = blockIdx.y;
  const int* s = y ? sb : sa;
  const int* d = y ? db : da;
  unsigned* p = pay + (size_t)y * kNBUK * kCAP;
  int* cn = cnt + y * kNBUK;
  __shared__ unsigned stash[6400];              // 25.6KB
  __shared__ int h[kNBUK];
  int t = threadIdx.x;
  if (t < kNBUK) h[t] = 0;
  __syncthreads();
  int e0 = blockIdx.x * 6400;
#pragma unroll 5
  for (int it = 0; it < 25; ++it) {
    int e = e0 + it * 256 + t;
    int sv = s[e], dv = d[e];
    int b = dv >> 9;
    stash[it * 256 + t] = (unsigned)sv | ((unsigned)(dv & 511) << 16) |
                          ((unsigned)b << 25);
    atomicAdd(&h[b], 1);
  }
  __syncthreads();
  if (t < kNBUK) h[t] = atomicAdd(&cn[t], h[t]);  // h becomes block's cursor
  __syncthreads();
#pragma unroll 5
  for (int it = 0; it < 25; ++it) {
    unsigned w = stash[it * 256 + t];
    int b = w >> 25;
    int slot = atomicAdd(&h[b], 1);
    p[b * kCAP + slot] = w & 0x1FFFFFFu;
  }
}

// k_bscan: exclusive scan of 2x98 bucket counts -> global es/rp bases.
__global__ __launch_bounds__(256)
void k_bscan(const int* __restrict__ cnt, int* __restrict__ bbase,
             int* __restrict__ rpa, int* __restrict__ rpb) {
  __shared__ int buf[2][128];
  int t = threadIdx.x;
  int y = t >> 7, i = t & 127;
  int x = (i < kNBUK) ? cnt[y * kNBUK + i] : 0;
  buf[y][i] = x;
  __syncthreads();
  for (int off = 1; off < 128; off <<= 1) {
    int v = (i >= off) ? buf[y][i - off] : 0;
    __syncthreads();
    buf[y][i] += v;
    __syncthreads();
  }
  if (i < kNBUK) bbase[y * kNBUK + i] = buf[y][i] - x;
  if (t == 0) { rpa[kN] = kE; rpb[kN] = kE; }
}

// k_bucket: one block per (bucket, graph). LDS histogram + pair scan ->
// writes rp segment AND scatters es via LDS cursor atomics.
__global__ __launch_bounds__(256)
void k_bucket(const int* __restrict__ cnt, const int* __restrict__ bbase,
              const unsigned* __restrict__ pay,
              int* __restrict__ rpa, int* __restrict__ rpb,
              int* __restrict__ esa, int* __restrict__ esb) {
  int b = blockIdx.x, y = blockIdx.y;
  int* rp = y ? rpb : rpa;
  int* es = y ? esb : esa;
  const unsigned* p = pay + ((size_t)y * kNBUK + b) * kCAP;
  int c = cnt[y * kNBUK + b];
  int base = bbase[y * kNBUK + b];
  __shared__ unsigned pl[kCAP];                 // 36.9KB
  __shared__ int h[512];
  __shared__ int buf[256];
  int t = threadIdx.x;
  h[t] = 0; h[t + 256] = 0;
  __syncthreads();
  for (int i = t; i < c; i += 256) {
    unsigned w = p[i];
    pl[i] = w;
    atomicAdd(&h[(w >> 16) & 511], 1);
  }
  __syncthreads();
  int a = h[2 * t], b1 = h[2 * t + 1];
  int s2 = a + b1;
  buf[t] = s2;
  __syncthreads();
  for (int off = 1; off < 256; off <<= 1) {
    int v = (t >= off) ? buf[t - off] : 0;
    __syncthreads();
    buf[t] += v;
    __syncthreads();
  }
  int ex = buf[t] - s2;                         // exclusive pair base
  int g0 = b * 512 + 2 * t;
  if (g0 < kN) rp[g0] = base + ex;
  if (g0 + 1 < kN) rp[g0 + 1] = base + ex + a;
  h[2 * t] = ex;                                // h becomes local cursors
  h[2 * t + 1] = ex + a;
  __syncthreads();
  for (int i = t; i < c; i += 256) {
    unsigned w = pl[i];
    int slot = atomicAdd(&h[(w >> 16) & 511], 1);
    es[base + slot] = (int)(w & 0xFFFFu);
  }
}

// ---------------- GAT aggregate (round-3 proven structure, per-graph) ------
__global__ __launch_bounds__(256)
void k_agg(const int* __restrict__ rp, const int* __restrict__ es,
           const float* __restrict__ el, const float* __restrict__ er,
           const unsigned short* __restrict__ feat,
           const float* __restrict__ bias,
           float* __restrict__ za, unsigned short* __restrict__ zb,
           int y) {
  __shared__ float wls[4][512];                // 64 edges x 8 heads per wave
  __shared__ int sls[4][64];
  int nb = blockIdx.x;
  int lane = threadIdx.x & 63;
  int wave = threadIdx.x >> 6;
  int n = nb * 4 + wave;
  int hh = lane >> 3;                          // phase1 edge-slot
  int h = lane & 7;                            // phase1 head
  int half = lane >> 5;                        // phase2: which edge of pair
  int l5 = lane & 31;
  int h2 = l5 >> 2;                            // phase2 head (dims l5*8..+7)
  unsigned idx16 = (unsigned)l5 * 16u;         // byte offset in feat row
  float erh = er[n * 8 + h];
  int e0 = rp[n], e1 = rp[n + 1];
  float dsum = 0.f;
  float a0 = 0.f, a1 = 0.f, a2 = 0.f, a3 = 0.f;
  float a4 = 0.f, a5 = 0.f, a6 = 0.f, a7 = 0.f;

  for (int cb = e0; cb < e1; cb += 64) {
    int cnt = e1 - cb;
    if (cnt > 64) cnt = 64;
    // phase 1: weights -> LDS, 8 edges/iter, no lane redundancy
    for (int it = 0; it * 8 < cnt; ++it) {
      int j = it * 8 + hh;
      if (j < cnt) {
        int s = es[cb + j];
        float ev = *(const float*)((const char*)el + ((unsigned)s << 5) +
                                   ((unsigned)h << 2)) + erh;
        ev = fmaxf(ev, 0.2f * ev);             // LeakyReLU(0.2)
        float w = __expf(ev);
        wls[wave][it * 64 + lane] = w;         // == [j*8 + h]
        if (h == 0) sls[wave][j] = s;
        dsum += w;
      }
    }
    // phase 2: 2 edges/instr, 16B/lane (same-wave LDS dep, no barrier)
    int j = 0;
    for (; j + 7 < cnt; j += 8) {
#pragma unroll
      for (int p = 0; p < 4; ++p) {
        int jj = j + 2 * p + half;
        int s = sls[wave][jj];
        float w = wls[wave][jj * 8 + h2];
        us8 fv = *(const us8*)((const char*)feat + (((unsigned)s << 9) + idx16));
        a0 += w * b2f(fv[0]);
        a1 += w * b2f(fv[1]);
        a2 += w * b2f(fv[2]);
        a3 += w * b2f(fv[3]);
        a4 += w * b2f(fv[4]);
        a5 += w * b2f(fv[5]);
        a6 += w * b2f(fv[6]);
        a7 += w * b2f(fv[7]);
      }
    }
    if (j < cnt) {
#pragma unroll
      for (int p = 0; p < 4; ++p) {
        int jj = j + 2 * p + half;
        bool v = jj < cnt;
        int jc = v ? jj : j;
        int s = sls[wave][jc];
        float w = v ? wls[wave][jc * 8 + h2] : 0.f;
        us8 fv = *(const us8*)((const char*)feat + (((unsigned)s << 9) + idx16));
        a0 += w * b2f(fv[0]);
        a1 += w * b2f(fv[1]);
        a2 += w * b2f(fv[2]);
        a3 += w * b2f(fv[3]);
        a4 += w * b2f(fv[4]);
        a5 += w * b2f(fv[5]);
        a6 += w * b2f(fv[6]);
        a7 += w * b2f(fv[7]);
      }
    }
  }
  // combine halves (each half holds alternating edges' partials)
  a0 += __shfl_xor(a0, 32); a1 += __shfl_xor(a1, 32);
  a2 += __shfl_xor(a2, 32); a3 += __shfl_xor(a3, 32);
  a4 += __shfl_xor(a4, 32); a5 += __shfl_xor(a5, 32);
  a6 += __shfl_xor(a6, 32); a7 += __shfl_xor(a7, 32);
  // denom: reduce over edge-slot bits; lane i holds head i&7 total
  dsum += __shfl_xor(dsum, 8);
  dsum += __shfl_xor(dsum, 16);
  dsum += __shfl_xor(dsum, 32);
  float dh = __shfl(dsum, h2);                 // this lane's head total
  float inv = __builtin_amdgcn_rcpf(dh > 0.f ? dh : 1.f);
  f32x4 blo = *(const f32x4*)(bias + l5 * 8);
  f32x4 bhi = *(const f32x4*)(bias + l5 * 8 + 4);
  float r0 = a0 * inv + blo.x;
  float r1 = a1 * inv + blo.y;
  float r2 = a2 * inv + blo.z;
  float r3 = a3 * inv + blo.w;
  float r4 = a4 * inv + bhi.x;
  float r5 = a5 * inv + bhi.y;
  float r6 = a6 * inv + bhi.z;
  float r7 = a7 * inv + bhi.w;
  r0 = r0 > 0.f ? r0 : __expf(r0) - 1.f;       // ELU (no libm)
  r1 = r1 > 0.f ? r1 : __expf(r1) - 1.f;
  r2 = r2 > 0.f ? r2 : __expf(r2) - 1.f;
  r3 = r3 > 0.f ? r3 : __expf(r3) - 1.f;
  r4 = r4 > 0.f ? r4 : __expf(r4) - 1.f;
  r5 = r5 > 0.f ? r5 : __expf(r5) - 1.f;
  r6 = r6 > 0.f ? r6 : __expf(r6) - 1.f;
  r7 = r7 > 0.f ? r7 : __expf(r7) - 1.f;
  f32x4 lo = {r0, r1, r2, r3};
  f32x4 hi = {r4, r5, r6, r7};
  f32x4 ov = half ? hi : lo;
  if (y == 0) {
    *(f32x4*)((char*)za + (size_t)n * 1024 + l5 * 32 + half * 16) = ov;
  } else {
    us4 o;
    o.x = f2b(ov.x); o.y = f2b(ov.y); o.z = f2b(ov.z); o.w = f2b(ov.w);
    *(us4*)((char*)zb + (size_t)n * 512 + l5 * 16 + half * 8) = o;
  }
}

// ---------------- semantic scores via MFMA ---------------------------------
// r11 post-mortem: register-held W1 was demoted by the compiler (VGPR=60 <
// the 64 needed) -> 219us all-idle. Revert to r10's PROVEN structure
// (independent waves, zero loop barriers, W1 in LDS) and fix r10's resource
// problem (188 VGPR + 64KB LDS -> 8.5% occupancy) by splitting hidden-j
// across blockIdx.y: each block handles 64 of 128 j -> 32KB LDS, acc[4],
// b1v/w2v[4]. Sum over j is separable; wacc atomics combine halves.
// A (za/zb) read twice, but r10 FETCH (39MB of 75MB logical) shows L3
// absorbs it. launch_bounds(256,4): VGPR cap 128.
__global__ __launch_bounds__(256, 4)
void k_sem(const float* __restrict__ za,
           const unsigned short* __restrict__ zb,
           const unsigned short* __restrict__ w1t,
           const float* __restrict__ b1,
           const float* __restrict__ W2,
           float* __restrict__ wacc) {
  __shared__ us8 w1l[2048];                     // 64 rows x 32 chunks, 32KB
  int t = threadIdx.x;
  int jbase = blockIdx.y * 64;                  // this block's j-half
  for (int i = t; i < 2048; i += 256) {
    int j = i >> 5, c = i & 31;                 // j local 0..63
    w1l[j * 32 + (c ^ (j & 7))] = ((const us8*)w1t)[(jbase + j) * 32 + c];
  }
  __syncthreads();
  int lane = t & 63, wave = t >> 6;
  int col = lane & 15, quad = lane >> 4;
  float b1v[4], w2v[4];
#pragma unroll
  for (int tt = 0; tt < 4; ++tt) {
    b1v[tt] = b1[jbase + tt * 16 + col];
    w2v[tt] = W2[jbase + tt * 16 + col];
  }
  int gw = blockIdx.x * 4 + wave;
  int nw = gridDim.x * 4;
  float sa = 0.f, sb = 0.f;
  for (int gt = gw; gt < 6250; gt += nw) {
    f32x4 acc[4];
#pragma unroll
    for (int tt = 0; tt < 4; ++tt) acc[tt] = (f32x4){0.f, 0.f, 0.f, 0.f};
#pragma unroll
    for (int ks = 0; ks < 8; ++ks) {
      bf16x8 a;
      if (gt < 3125) {
        const float* ap = za + (size_t)gt * 4096 + col * 256 + ks * 32 + quad * 8;
        f32x4 a0 = *(const f32x4*)ap;
        f32x4 a1 = *(const f32x4*)(ap + 4);
        a[0] = (short)f2b(a0.x); a[1] = (short)f2b(a0.y);
        a[2] = (short)f2b(a0.z); a[3] = (short)f2b(a0.w);
        a[4] = (short)f2b(a1.x); a[5] = (short)f2b(a1.y);
        a[6] = (short)f2b(a1.z); a[7] = (short)f2b(a1.w);
      } else {
        a = *(const bf16x8*)(zb + (size_t)(gt - 3125) * 4096 + col * 256 +
                             ks * 32 + quad * 8);
      }
      int c = ks * 4 + quad;
#pragma unroll
      for (int tt = 0; tt < 4; ++tt) {
        int j = tt * 16 + col;                  // local j
        bf16x8 b = (bf16x8)w1l[j * 32 + (c ^ (j & 7))];
        acc[tt] = __builtin_amdgcn_mfma_f32_16x16x32_bf16(a, b, acc[tt], 0, 0, 0);
      }
    }
    float tot = 0.f;
#pragma unroll
    for (int tt = 0; tt < 4; ++tt)
#pragma unroll
      for (int r = 0; r < 4; ++r) {
        float x = acc[tt][r] + b1v[tt];
        x = fminf(fmaxf(x, -10.f), 10.f);       // clamp for exp overflow
        float ex = __expf(2.f * x);             // tanh = (e^2x-1)/(e^2x+1)
        tot += (ex - 1.f) * __builtin_amdgcn_rcpf(ex + 1.f) * w2v[tt];
      }
#pragma unroll
    for (int off = 1; off < 64; off <<= 1) tot += __shfl_xor(tot, off);
    if (gt < 3125) sa += tot; else sb += tot;
  }
  if (lane == 0) {
    if (sa != 0.f) atomicAdd(&wacc[0], sa);
    if (sb != 0.f) atomicAdd(&wacc[1], sb);
  }
}

// ---------------- beta softmax + combine (in-place over za==out) -----------
__global__ __launch_bounds__(256)
void k_combine(const float* __restrict__ za,
               const unsigned short* __restrict__ zb,
               const float* __restrict__ wacc,
               float* __restrict__ out) {
  int i = blockIdx.x * 256 + threadIdx.x;       // 3.2M groups of 4
  float wa = wacc[0] * (1.f / kN), wb = wacc[1] * (1.f / kN);
  float mx = fmaxf(wa, wb);
  float ea = __expf(wa - mx), eb = __expf(wb - mx);
  float inv = __builtin_amdgcn_rcpf(ea + eb);
  float ba = ea * inv, bb = eb * inv;
  f32x4 x = ((const f32x4*)za)[i];
  us4 yv = ((const us4*)zb)[i];
  f32x4 o;
#pragma unroll
  for (int j = 0; j < 4; ++j)
    o[j] = ba * x[j] + bb * b2f(yv[j]);
  ((f32x4*)out)[i] = o;
}

extern "C" void kernel_launch(void* const* d_in, const int* in_sizes, int n_in,
                              void* d_out, int out_size, void* d_ws, size_t ws_size,
                              hipStream_t stream) {
  const float* hin = (const float*)d_in[0];
  const int* src_a = (const int*)d_in[1];
  const int* dst_a = (const int*)d_in[2];
  const int* src_b = (const int*)d_in[3];
  const int* dst_b = (const int*)d_in[4];
  const float* W_a = (const float*)d_in[5];
  const float* al_a = (const float*)d_in[6];
  const float* ar_a = (const float*)d_in[7];
  const float* bias_a = (const float*)d_in[8];
  const float* W_b = (const float*)d_in[9];
  const float* al_b = (const float*)d_in[10];
  const float* ar_b = (const float*)d_in[11];
  const float* bias_b = (const float*)d_in[12];
  const float* sW1 = (const float*)d_in[13];
  const float* sb1 = (const float*)d_in[14];
  const float* sW2 = (const float*)d_in[15];
  float* out = (float*)d_out;

  char* wsb = (char*)d_ws;
  size_t off = 0;
  auto alloc = [&](size_t bytes) -> char* {
    char* p = wsb + off;
    off = (off + bytes + 511) & ~(size_t)511;
    return p;
  };
  // Footprint ~98 MB.
  unsigned short* feat_a = (unsigned short*)alloc((size_t)kN * 256 * 2); // 25.6MB
  unsigned short* feat_b = (unsigned short*)alloc((size_t)kN * 256 * 2); // 25.6MB
  unsigned short* z_b    = (unsigned short*)alloc((size_t)kN * 256 * 2); // 25.6MB
  float* el_a = (float*)alloc((size_t)kN * 8 * 4);
  float* er_a = (float*)alloc((size_t)kN * 8 * 4);
  float* el_b = (float*)alloc((size_t)kN * 8 * 4);
  float* er_b = (float*)alloc((size_t)kN * 8 * 4);
  unsigned short* wt_a = (unsigned short*)alloc(65536 * 2);
  unsigned short* wt_b = (unsigned short*)alloc(65536 * 2);
  unsigned short* w1t  = (unsigned short*)alloc(32768 * 2);
  int* rp_a = (int*)alloc((size_t)(kN + 1) * 4);
  int* rp_b = (int*)alloc((size_t)(kN + 1) * 4);
  int* es_a = (int*)alloc((size_t)kE * 4);
  int* es_b = (int*)alloc((size_t)kE * 4);
  unsigned* pay = (unsigned*)alloc((size_t)2 * kNBUK * kCAP * 4);  // 7.2MB
  int* cnt = (int*)alloc((size_t)2 * kNBUK * 4);
  int* bbase = (int*)alloc((size_t)2 * kNBUK * 4);
  float* wacc = (float*)alloc(2 * 4);

  hipMemsetAsync(cnt, 0, (size_t)2 * kNBUK * 4, stream);
  hipMemsetAsync(wacc, 0, 8, stream);

  k_prep<<<640, 256, 0, stream>>>(W_a, W_b, sW1, wt_a, wt_b, w1t);
  k_part<<<dim3(125, 2), 256, 0, stream>>>(src_a, dst_a, src_b, dst_b, cnt, pay);
  k_bscan<<<1, 256, 0, stream>>>(cnt, bbase, rp_a, rp_b);
  k_bucket<<<dim3(kNBUK, 2), 256, 0, stream>>>(cnt, bbase, pay,
                                               rp_a, rp_b, es_a, es_b);
  k_gemm<<<dim3(782, 2), 512, 0, stream>>>(hin, wt_a, wt_b,
                                           al_a, ar_a, al_b, ar_b,
                                           feat_a, feat_b,
                                           el_a, er_a, el_b, er_b);
  k_agg<<<12500, 256, 0, stream>>>(rp_a, es_a, el_a, er_a, feat_a, bias_a,
                                   out, z_b, 0);
  k_agg<<<12500, 256, 0, stream>>>(rp_b, es_b, el_b, er_b, feat_b, bias_b,
                                   out, z_b, 1);
  k_sem<<<dim3(512, 2), 256, 0, stream>>>(out, z_b, w1t, sb1, sW2, wacc);
  k_combine<<<12500, 256, 0, stream>>>(out, z_b, wacc, out);
}

// Round 13
// 496.400 us; speedup vs baseline: 1.1871x; 1.0683x over previous
//
#include <hip/hip_runtime.h>
#include <math.h>

typedef __attribute__((ext_vector_type(8))) short bf16x8;
typedef __attribute__((ext_vector_type(4))) float f32x4;
typedef __attribute__((ext_vector_type(4))) unsigned short us4;
typedef __attribute__((ext_vector_type(8))) unsigned short us8;

static constexpr int kN  = 50000;
static constexpr int kE  = 800000;
static constexpr int kNBUK = 98;     // ceil(50000/512), bucket = dst>>9
static constexpr int kCAP  = 9216;   // per-bucket payload cap (mean 8163 + 11.6 sigma)

__device__ __forceinline__ float b2f(unsigned short u) {
  union { unsigned u; float f; } x; x.u = ((unsigned)u) << 16; return x.f;
}
__device__ __forceinline__ unsigned short f2b(float f) {
  union { float f; unsigned u; } x; x.f = f;
  unsigned u = x.u;
  unsigned r = (u + 0x7fffu + ((u >> 16) & 1u)) >> 16;
  return (unsigned short)r;
}

// ---------------- fused prep: Wt_a, Wt_b (bf16 [256][256]), W1T (bf16 [128][256])
__global__ __launch_bounds__(256)
void k_prep(const float* __restrict__ Wa, const float* __restrict__ Wb,
            const float* __restrict__ W1,
            unsigned short* __restrict__ wta, unsigned short* __restrict__ wtb,
            unsigned short* __restrict__ w1t) {
  int b = blockIdx.x, t = threadIdx.x;
  if (b < 256) {
    int i = b * 256 + t, j = i >> 8, k = i & 255;
    wta[j * 256 + k] = f2b(Wa[k * 256 + j]);
  } else if (b < 512) {
    int i = (b - 256) * 256 + t, j = i >> 8, k = i & 255;
    wtb[j * 256 + k] = f2b(Wb[k * 256 + j]);
  } else {
    int i = (b - 512) * 256 + t, j = i >> 8, k = i & 255;  // j<128
    w1t[j * 256 + k] = f2b(W1[k * 128 + j]);
  }
}

// ---------------- feat = h @ W + fused el/er (r10 passing version) ---------
__global__ __launch_bounds__(512, 6)
void k_gemm(const float* __restrict__ h,
            const unsigned short* __restrict__ wta,
            const unsigned short* __restrict__ wtb,
            const float* __restrict__ ala, const float* __restrict__ ara,
            const float* __restrict__ alb, const float* __restrict__ arb,
            unsigned short* __restrict__ fa, unsigned short* __restrict__ fb,
            float* __restrict__ ela, float* __restrict__ era,
            float* __restrict__ elb, float* __restrict__ erb) {
  __shared__ us8 la[64 * 8];                   // 8KB
  __shared__ us8 lbb[256 * 8];                 // 32KB
  const int z = blockIdx.y;
  const unsigned short* wt = z ? wtb : wta;
  unsigned short* f = z ? fb : fa;
  const float* al = z ? alb : ala;
  const float* ar = z ? arb : ara;
  float* el = z ? elb : ela;
  float* er = z ? erb : era;
  const int m0 = blockIdx.x * 64;
  const int t = threadIdx.x;
  const int lane = t & 63;
  const int wave = t >> 6;                     // 0..7 == head
  const int col = lane & 15;
  const int quad = lane >> 4;
  const int nw = wave * 32;                    // this wave's 32 cols
  f32x4 acc[4][2];
#pragma unroll
  for (int i = 0; i < 4; ++i)
#pragma unroll
    for (int j = 0; j < 2; ++j) acc[i][j] = (f32x4){0.f, 0.f, 0.f, 0.f};

  for (int ks = 0; ks < 4; ++ks) {
    const int k0 = ks * 64;
    __syncthreads();
    // stage A: 64 rows x 64 k, fp32 -> bf16. 1024 8B-units, 2 iters.
#pragma unroll
    for (int i = 0; i < 2; ++i) {
      int idx = i * 512 + t;
      int r = idx >> 4, g = (idx >> 1) & 7, half = idx & 1;
      int gr = m0 + r;
      f32x4 v = {0.f, 0.f, 0.f, 0.f};
      if (gr < kN) v = *(const f32x4*)(h + (size_t)gr * 256 + k0 + g * 8 + half * 4);
      us4 o;
      o.x = f2b(v.x); o.y = f2b(v.y); o.z = f2b(v.z); o.w = f2b(v.w);
      *(us4*)((unsigned short*)&la[r * 8 + (g ^ (r & 7))] + half * 4) = o;
    }
    // stage B: 256 rows x 64 k bf16. 2048 16B-units, 4 iters.
#pragma unroll
    for (int i = 0; i < 4; ++i) {
      int idx = i * 512 + t;
      int r = idx >> 3, g = idx & 7;
      lbb[r * 8 + (g ^ (r & 7))] = *(const us8*)(wt + r * 256 + k0 + g * 8);
    }
    __syncthreads();
#pragma unroll
    for (int k32 = 0; k32 < 64; k32 += 32) {
      const int cg = (k32 >> 3) + quad;
      bf16x8 af[4], bf[2];
#pragma unroll
      for (int s = 0; s < 4; ++s) {
        int arow = s * 16 + col;
        af[s] = (bf16x8)la[arow * 8 + (cg ^ (arow & 7))];
      }
#pragma unroll
      for (int j = 0; j < 2; ++j) {
        int brow = nw + j * 16 + col;
        bf[j] = (bf16x8)lbb[brow * 8 + (cg ^ (brow & 7))];
      }
#pragma unroll
      for (int i = 0; i < 4; ++i)
#pragma unroll
        for (int j = 0; j < 2; ++j)
          acc[i][j] = __builtin_amdgcn_mfma_f32_16x16x32_bf16(af[i], bf[j],
                                                              acc[i][j], 0, 0, 0);
    }
  }
  // epilogue 1: feat store (C row = quad*4+reg, col = lane&15)
#pragma unroll
  for (int i = 0; i < 4; ++i) {
#pragma unroll
    for (int r = 0; r < 4; ++r) {
      int row = m0 + i * 16 + quad * 4 + r;
      if (row < kN) {
#pragma unroll
        for (int j = 0; j < 2; ++j)
          f[(size_t)row * 256 + nw + j * 16 + col] = f2b(acc[i][j][r]);
      }
    }
  }
  // epilogue 2: el/er for this wave's single head (cols nw..nw+31)
  float alv[2], arv[2];
#pragma unroll
  for (int j = 0; j < 2; ++j) {
    alv[j] = al[nw + j * 16 + col];
    arv[j] = ar[nw + j * 16 + col];
  }
#pragma unroll
  for (int i = 0; i < 4; ++i) {
#pragma unroll
    for (int r = 0; r < 4; ++r) {
      float pl = acc[i][0][r] * alv[0] + acc[i][1][r] * alv[1];
      float pr = acc[i][0][r] * arv[0] + acc[i][1][r] * arv[1];
#pragma unroll
      for (int off = 1; off < 16; off <<= 1) {
        pl += __shfl_xor(pl, off);
        pr += __shfl_xor(pr, off);
      }
      int row = m0 + i * 16 + quad * 4 + r;
      if (col == 0 && row < kN) {
        el[row * 8 + wave] = pl;
        er[row * 8 + wave] = pr;
      }
    }
  }
}

// ---------------- CSR build via radix partition ----------------------------
__global__ __launch_bounds__(256)
void k_part(const int* __restrict__ sa, const int* __restrict__ da,
            const int* __restrict__ sb, const int* __restrict__ db,
            int* __restrict__ cnt, unsigned* __restrict__ pay) {
  int y = blockIdx.y;
  const int* s = y ? sb : sa;
  const int* d = y ? db : da;
  unsigned* p = pay + (size_t)y * kNBUK * kCAP;
  int* cn = cnt + y * kNBUK;
  __shared__ unsigned stash[6400];              // 25.6KB
  __shared__ int h[kNBUK];
  int t = threadIdx.x;
  if (t < kNBUK) h[t] = 0;
  __syncthreads();
  int e0 = blockIdx.x * 6400;
#pragma unroll 5
  for (int it = 0; it < 25; ++it) {
    int e = e0 + it * 256 + t;
    int sv = s[e], dv = d[e];
    int b = dv >> 9;
    stash[it * 256 + t] = (unsigned)sv | ((unsigned)(dv & 511) << 16) |
                          ((unsigned)b << 25);
    atomicAdd(&h[b], 1);
  }
  __syncthreads();
  if (t < kNBUK) h[t] = atomicAdd(&cn[t], h[t]);  // h becomes block's cursor
  __syncthreads();
#pragma unroll 5
  for (int it = 0; it < 25; ++it) {
    unsigned w = stash[it * 256 + t];
    int b = w >> 25;
    int slot = atomicAdd(&h[b], 1);
    p[b * kCAP + slot] = w & 0x1FFFFFFu;
  }
}

// k_bscan: exclusive scan of 2x98 bucket counts -> global es/rp bases.
__global__ __launch_bounds__(256)
void k_bscan(const int* __restrict__ cnt, int* __restrict__ bbase,
             int* __restrict__ rpa, int* __restrict__ rpb) {
  __shared__ int buf[2][128];
  int t = threadIdx.x;
  int y = t >> 7, i = t & 127;
  int x = (i < kNBUK) ? cnt[y * kNBUK + i] : 0;
  buf[y][i] = x;
  __syncthreads();
  for (int off = 1; off < 128; off <<= 1) {
    int v = (i >= off) ? buf[y][i - off] : 0;
    __syncthreads();
    buf[y][i] += v;
    __syncthreads();
  }
  if (i < kNBUK) bbase[y * kNBUK + i] = buf[y][i] - x;
  if (t == 0) { rpa[kN] = kE; rpb[kN] = kE; }
}

// k_bucket: one block per (bucket, graph). LDS histogram + pair scan ->
// writes rp segment AND scatters es via LDS cursor atomics.
__global__ __launch_bounds__(256)
void k_bucket(const int* __restrict__ cnt, const int* __restrict__ bbase,
              const unsigned* __restrict__ pay,
              int* __restrict__ rpa, int* __restrict__ rpb,
              int* __restrict__ esa, int* __restrict__ esb) {
  int b = blockIdx.x, y = blockIdx.y;
  int* rp = y ? rpb : rpa;
  int* es = y ? esb : esa;
  const unsigned* p = pay + ((size_t)y * kNBUK + b) * kCAP;
  int c = cnt[y * kNBUK + b];
  int base = bbase[y * kNBUK + b];
  __shared__ unsigned pl[kCAP];                 // 36.9KB
  __shared__ int h[512];
  __shared__ int buf[256];
  int t = threadIdx.x;
  h[t] = 0; h[t + 256] = 0;
  __syncthreads();
  for (int i = t; i < c; i += 256) {
    unsigned w = p[i];
    pl[i] = w;
    atomicAdd(&h[(w >> 16) & 511], 1);
  }
  __syncthreads();
  int a = h[2 * t], b1 = h[2 * t + 1];
  int s2 = a + b1;
  buf[t] = s2;
  __syncthreads();
  for (int off = 1; off < 256; off <<= 1) {
    int v = (t >= off) ? buf[t - off] : 0;
    __syncthreads();
    buf[t] += v;
    __syncthreads();
  }
  int ex = buf[t] - s2;                         // exclusive pair base
  int g0 = b * 512 + 2 * t;
  if (g0 < kN) rp[g0] = base + ex;
  if (g0 + 1 < kN) rp[g0 + 1] = base + ex + a;
  h[2 * t] = ex;                                // h becomes local cursors
  h[2 * t + 1] = ex + a;
  __syncthreads();
  for (int i = t; i < c; i += 256) {
    unsigned w = pl[i];
    int slot = atomicAdd(&h[(w >> 16) & 511], 1);
    es[base + slot] = (int)(w & 0xFFFFu);
  }
}

// ---------------- GAT aggregate (round-3 proven structure, per-graph) ------
__global__ __launch_bounds__(256)
void k_agg(const int* __restrict__ rp, const int* __restrict__ es,
           const float* __restrict__ el, const float* __restrict__ er,
           const unsigned short* __restrict__ feat,
           const float* __restrict__ bias,
           float* __restrict__ za, unsigned short* __restrict__ zb,
           int y) {
  __shared__ float wls[4][512];                // 64 edges x 8 heads per wave
  __shared__ int sls[4][64];
  int nb = blockIdx.x;
  int lane = threadIdx.x & 63;
  int wave = threadIdx.x >> 6;
  int n = nb * 4 + wave;
  int hh = lane >> 3;                          // phase1 edge-slot
  int h = lane & 7;                            // phase1 head
  int half = lane >> 5;                        // phase2: which edge of pair
  int l5 = lane & 31;
  int h2 = l5 >> 2;                            // phase2 head (dims l5*8..+7)
  unsigned idx16 = (unsigned)l5 * 16u;         // byte offset in feat row
  float erh = er[n * 8 + h];
  int e0 = rp[n], e1 = rp[n + 1];
  float dsum = 0.f;
  float a0 = 0.f, a1 = 0.f, a2 = 0.f, a3 = 0.f;
  float a4 = 0.f, a5 = 0.f, a6 = 0.f, a7 = 0.f;

  for (int cb = e0; cb < e1; cb += 64) {
    int cnt = e1 - cb;
    if (cnt > 64) cnt = 64;
    // phase 1: weights -> LDS, 8 edges/iter, no lane redundancy
    for (int it = 0; it * 8 < cnt; ++it) {
      int j = it * 8 + hh;
      if (j < cnt) {
        int s = es[cb + j];
        float ev = *(const float*)((const char*)el + ((unsigned)s << 5) +
                                   ((unsigned)h << 2)) + erh;
        ev = fmaxf(ev, 0.2f * ev);             // LeakyReLU(0.2)
        float w = __expf(ev);
        wls[wave][it * 64 + lane] = w;         // == [j*8 + h]
        if (h == 0) sls[wave][j] = s;
        dsum += w;
      }
    }
    // phase 2: 2 edges/instr, 16B/lane (same-wave LDS dep, no barrier)
    int j = 0;
    for (; j + 7 < cnt; j += 8) {
#pragma unroll
      for (int p = 0; p < 4; ++p) {
        int jj = j + 2 * p + half;
        int s = sls[wave][jj];
        float w = wls[wave][jj * 8 + h2];
        us8 fv = *(const us8*)((const char*)feat + (((unsigned)s << 9) + idx16));
        a0 += w * b2f(fv[0]);
        a1 += w * b2f(fv[1]);
        a2 += w * b2f(fv[2]);
        a3 += w * b2f(fv[3]);
        a4 += w * b2f(fv[4]);
        a5 += w * b2f(fv[5]);
        a6 += w * b2f(fv[6]);
        a7 += w * b2f(fv[7]);
      }
    }
    if (j < cnt) {
#pragma unroll
      for (int p = 0; p < 4; ++p) {
        int jj = j + 2 * p + half;
        bool v = jj < cnt;
        int jc = v ? jj : j;
        int s = sls[wave][jc];
        float w = v ? wls[wave][jc * 8 + h2] : 0.f;
        us8 fv = *(const us8*)((const char*)feat + (((unsigned)s << 9) + idx16));
        a0 += w * b2f(fv[0]);
        a1 += w * b2f(fv[1]);
        a2 += w * b2f(fv[2]);
        a3 += w * b2f(fv[3]);
        a4 += w * b2f(fv[4]);
        a5 += w * b2f(fv[5]);
        a6 += w * b2f(fv[6]);
        a7 += w * b2f(fv[7]);
      }
    }
  }
  // combine halves (each half holds alternating edges' partials)
  a0 += __shfl_xor(a0, 32); a1 += __shfl_xor(a1, 32);
  a2 += __shfl_xor(a2, 32); a3 += __shfl_xor(a3, 32);
  a4 += __shfl_xor(a4, 32); a5 += __shfl_xor(a5, 32);
  a6 += __shfl_xor(a6, 32); a7 += __shfl_xor(a7, 32);
  // denom: reduce over edge-slot bits; lane i holds head i&7 total
  dsum += __shfl_xor(dsum, 8);
  dsum += __shfl_xor(dsum, 16);
  dsum += __shfl_xor(dsum, 32);
  float dh = __shfl(dsum, h2);                 // this lane's head total
  float inv = __builtin_amdgcn_rcpf(dh > 0.f ? dh : 1.f);
  f32x4 blo = *(const f32x4*)(bias + l5 * 8);
  f32x4 bhi = *(const f32x4*)(bias + l5 * 8 + 4);
  float r0 = a0 * inv + blo.x;
  float r1 = a1 * inv + blo.y;
  float r2 = a2 * inv + blo.z;
  float r3 = a3 * inv + blo.w;
  float r4 = a4 * inv + bhi.x;
  float r5 = a5 * inv + bhi.y;
  float r6 = a6 * inv + bhi.z;
  float r7 = a7 * inv + bhi.w;
  r0 = r0 > 0.f ? r0 : __expf(r0) - 1.f;       // ELU (no libm)
  r1 = r1 > 0.f ? r1 : __expf(r1) - 1.f;
  r2 = r2 > 0.f ? r2 : __expf(r2) - 1.f;
  r3 = r3 > 0.f ? r3 : __expf(r3) - 1.f;
  r4 = r4 > 0.f ? r4 : __expf(r4) - 1.f;
  r5 = r5 > 0.f ? r5 : __expf(r5) - 1.f;
  r6 = r6 > 0.f ? r6 : __expf(r6) - 1.f;
  r7 = r7 > 0.f ? r7 : __expf(r7) - 1.f;
  f32x4 lo = {r0, r1, r2, r3};
  f32x4 hi = {r4, r5, r6, r7};
  f32x4 ov = half ? hi : lo;
  if (y == 0) {
    *(f32x4*)((char*)za + (size_t)n * 1024 + l5 * 32 + half * 16) = ov;
  } else {
    us4 o;
    o.x = f2b(ov.x); o.y = f2b(ov.y); o.z = f2b(ov.z); o.w = f2b(ov.w);
    *(us4*)((char*)zb + (size_t)n * 512 + l5 * 16 + half * 8) = o;
  }
}

// ---------------- semantic scores via MFMA ---------------------------------
// r12 post-mortem: launch_bounds(256,4) forced a 60-64 VGPR target on a
// ~120-reg live set -> scratch spills (WRITE 60MB in a kernel that writes 8B;
// FETCH +108MB of spill re-reads). Fix: UNCAPPED launch_bounds(256), exactly
// like the working r10 (188 VGPR, no spill). The blockIdx.y j-split stays:
// 64 of 128 hidden-j per block -> 32KB LDS, acc[4], natural VGPR ~150.
__global__ __launch_bounds__(256)
void k_sem(const float* __restrict__ za,
           const unsigned short* __restrict__ zb,
           const unsigned short* __restrict__ w1t,
           const float* __restrict__ b1,
           const float* __restrict__ W2,
           float* __restrict__ wacc) {
  __shared__ us8 w1l[2048];                     // 64 rows x 32 chunks, 32KB
  int t = threadIdx.x;
  int jbase = blockIdx.y * 64;                  // this block's j-half
  for (int i = t; i < 2048; i += 256) {
    int j = i >> 5, c = i & 31;                 // j local 0..63
    w1l[j * 32 + (c ^ (j & 7))] = ((const us8*)w1t)[(jbase + j) * 32 + c];
  }
  __syncthreads();
  int lane = t & 63, wave = t >> 6;
  int col = lane & 15, quad = lane >> 4;
  float b1v[4], w2v[4];
#pragma unroll
  for (int tt = 0; tt < 4; ++tt) {
    b1v[tt] = b1[jbase + tt * 16 + col];
    w2v[tt] = W2[jbase + tt * 16 + col];
  }
  int gw = blockIdx.x * 4 + wave;
  int nw = gridDim.x * 4;
  float sa = 0.f, sb = 0.f;
  for (int gt = gw; gt < 6250; gt += nw) {
    f32x4 acc[4];
#pragma unroll
    for (int tt = 0; tt < 4; ++tt) acc[tt] = (f32x4){0.f, 0.f, 0.f, 0.f};
#pragma unroll
    for (int ks = 0; ks < 8; ++ks) {
      bf16x8 a;
      if (gt < 3125) {
        const float* ap = za + (size_t)gt * 4096 + col * 256 + ks * 32 + quad * 8;
        f32x4 a0 = *(const f32x4*)ap;
        f32x4 a1 = *(const f32x4*)(ap + 4);
        a[0] = (short)f2b(a0.x); a[1] = (short)f2b(a0.y);
        a[2] = (short)f2b(a0.z); a[3] = (short)f2b(a0.w);
        a[4] = (short)f2b(a1.x); a[5] = (short)f2b(a1.y);
        a[6] = (short)f2b(a1.z); a[7] = (short)f2b(a1.w);
      } else {
        a = *(const bf16x8*)(zb + (size_t)(gt - 3125) * 4096 + col * 256 +
                             ks * 32 + quad * 8);
      }
      int c = ks * 4 + quad;
#pragma unroll
      for (int tt = 0; tt < 4; ++tt) {
        int j = tt * 16 + col;                  // local j
        bf16x8 b = (bf16x8)w1l[j * 32 + (c ^ (j & 7))];
        acc[tt] = __builtin_amdgcn_mfma_f32_16x16x32_bf16(a, b, acc[tt], 0, 0, 0);
      }
    }
    float tot = 0.f;
#pragma unroll
    for (int tt = 0; tt < 4; ++tt)
#pragma unroll
      for (int r = 0; r < 4; ++r) {
        float x = acc[tt][r] + b1v[tt];
        x = fminf(fmaxf(x, -10.f), 10.f);       // clamp for exp overflow
        float ex = __expf(2.f * x);             // tanh = (e^2x-1)/(e^2x+1)
        tot += (ex - 1.f) * __builtin_amdgcn_rcpf(ex + 1.f) * w2v[tt];
      }
#pragma unroll
    for (int off = 1; off < 64; off <<= 1) tot += __shfl_xor(tot, off);
    if (gt < 3125) sa += tot; else sb += tot;
  }
  if (lane == 0) {
    if (sa != 0.f) atomicAdd(&wacc[0], sa);
    if (sb != 0.f) atomicAdd(&wacc[1], sb);
  }
}

// ---------------- beta softmax + combine (in-place over za==out) -----------
__global__ __launch_bounds__(256)
void k_combine(const float* __restrict__ za,
               const unsigned short* __restrict__ zb,
               const float* __restrict__ wacc,
               float* __restrict__ out) {
  int i = blockIdx.x * 256 + threadIdx.x;       // 3.2M groups of 4
  float wa = wacc[0] * (1.f / kN), wb = wacc[1] * (1.f / kN);
  float mx = fmaxf(wa, wb);
  float ea = __expf(wa - mx), eb = __expf(wb - mx);
  float inv = __builtin_amdgcn_rcpf(ea + eb);
  float ba = ea * inv, bb = eb * inv;
  f32x4 x = ((const f32x4*)za)[i];
  us4 yv = ((const us4*)zb)[i];
  f32x4 o;
#pragma unroll
  for (int j = 0; j < 4; ++j)
    o[j] = ba * x[j] + bb * b2f(yv[j]);
  ((f32x4*)out)[i] = o;
}

extern "C" void kernel_launch(void* const* d_in, const int* in_sizes, int n_in,
                              void* d_out, int out_size, void* d_ws, size_t ws_size,
                              hipStream_t stream) {
  const float* hin = (const float*)d_in[0];
  const int* src_a = (const int*)d_in[1];
  const int* dst_a = (const int*)d_in[2];
  const int* src_b = (const int*)d_in[3];
  const int* dst_b = (const int*)d_in[4];
  const float* W_a = (const float*)d_in[5];
  const float* al_a = (const float*)d_in[6];
  const float* ar_a = (const float*)d_in[7];
  const float* bias_a = (const float*)d_in[8];
  const float* W_b = (const float*)d_in[9];
  const float* al_b = (const float*)d_in[10];
  const float* ar_b = (const float*)d_in[11];
  const float* bias_b = (const float*)d_in[12];
  const float* sW1 = (const float*)d_in[13];
  const float* sb1 = (const float*)d_in[14];
  const float* sW2 = (const float*)d_in[15];
  float* out = (float*)d_out;

  char* wsb = (char*)d_ws;
  size_t off = 0;
  auto alloc = [&](size_t bytes) -> char* {
    char* p = wsb + off;
    off = (off + bytes + 511) & ~(size_t)511;
    return p;
  };
  // Footprint ~98 MB.
  unsigned short* feat_a = (unsigned short*)alloc((size_t)kN * 256 * 2); // 25.6MB
  unsigned short* feat_b = (unsigned short*)alloc((size_t)kN * 256 * 2); // 25.6MB
  unsigned short* z_b    = (unsigned short*)alloc((size_t)kN * 256 * 2); // 25.6MB
  float* el_a = (float*)alloc((size_t)kN * 8 * 4);
  float* er_a = (float*)alloc((size_t)kN * 8 * 4);
  float* el_b = (float*)alloc((size_t)kN * 8 * 4);
  float* er_b = (float*)alloc((size_t)kN * 8 * 4);
  unsigned short* wt_a = (unsigned short*)alloc(65536 * 2);
  unsigned short* wt_b = (unsigned short*)alloc(65536 * 2);
  unsigned short* w1t  = (unsigned short*)alloc(32768 * 2);
  int* rp_a = (int*)alloc((size_t)(kN + 1) * 4);
  int* rp_b = (int*)alloc((size_t)(kN + 1) * 4);
  int* es_a = (int*)alloc((size_t)kE * 4);
  int* es_b = (int*)alloc((size_t)kE * 4);
  unsigned* pay = (unsigned*)alloc((size_t)2 * kNBUK * kCAP * 4);  // 7.2MB
  int* cnt = (int*)alloc((size_t)2 * kNBUK * 4);
  int* bbase = (int*)alloc((size_t)2 * kNBUK * 4);
  float* wacc = (float*)alloc(2 * 4);

  hipMemsetAsync(cnt, 0, (size_t)2 * kNBUK * 4, stream);
  hipMemsetAsync(wacc, 0, 8, stream);

  k_prep<<<640, 256, 0, stream>>>(W_a, W_b, sW1, wt_a, wt_b, w1t);
  k_part<<<dim3(125, 2), 256, 0, stream>>>(src_a, dst_a, src_b, dst_b, cnt, pay);
  k_bscan<<<1, 256, 0, stream>>>(cnt, bbase, rp_a, rp_b);
  k_bucket<<<dim3(kNBUK, 2), 256, 0, stream>>>(cnt, bbase, pay,
                                               rp_a, rp_b, es_a, es_b);
  k_gemm<<<dim3(782, 2), 512, 0, stream>>>(hin, wt_a, wt_b,
                                           al_a, ar_a, al_b, ar_b,
                                           feat_a, feat_b,
                                           el_a, er_a, el_b, er_b);
  k_agg<<<12500, 256, 0, stream>>>(rp_a, es_a, el_a, er_a, feat_a, bias_a,
                                   out, z_b, 0);
  k_agg<<<12500, 256, 0, stream>>>(rp_b, es_b, el_b, er_b, feat_b, bias_b,
                                   out, z_b, 1);
  k_sem<<<dim3(512, 2), 256, 0, stream>>>(out, z_b, w1t, sb1, sW2, wacc);
  k_combine<<<12500, 256, 0, stream>>>(out, z_b, wacc, out);
}

// Round 14
// 424.544 us; speedup vs baseline: 1.3880x; 1.1693x over previous
//
#include <hip/hip_runtime.h>
#include <math.h>

typedef __attribute__((ext_vector_type(8))) short bf16x8;
typedef __attribute__((ext_vector_type(4))) float f32x4;
typedef __attribute__((ext_vector_type(4))) unsigned short us4;
typedef __attribute__((ext_vector_type(8))) unsigned short us8;

static constexpr int kN  = 50000;
static constexpr int kE  = 800000;
static constexpr int kNBUK = 98;     // ceil(50000/512), bucket = dst>>9
static constexpr int kCAP  = 9216;   // per-bucket payload cap (mean 8163 + 11.6 sigma)

__device__ __forceinline__ float b2f(unsigned short u) {
  union { unsigned u; float f; } x; x.u = ((unsigned)u) << 16; return x.f;
}
__device__ __forceinline__ unsigned short f2b(float f) {
  union { float f; unsigned u; } x; x.f = f;
  unsigned u = x.u;
  unsigned r = (u + 0x7fffu + ((u >> 16) & 1u)) >> 16;
  return (unsigned short)r;
}

// ---------------- fused prep: Wt_a, Wt_b (bf16 [256][256]), W1T (bf16 [128][256])
__global__ __launch_bounds__(256)
void k_prep(const float* __restrict__ Wa, const float* __restrict__ Wb,
            const float* __restrict__ W1,
            unsigned short* __restrict__ wta, unsigned short* __restrict__ wtb,
            unsigned short* __restrict__ w1t) {
  int b = blockIdx.x, t = threadIdx.x;
  if (b < 256) {
    int i = b * 256 + t, j = i >> 8, k = i & 255;
    wta[j * 256 + k] = f2b(Wa[k * 256 + j]);
  } else if (b < 512) {
    int i = (b - 256) * 256 + t, j = i >> 8, k = i & 255;
    wtb[j * 256 + k] = f2b(Wb[k * 256 + j]);
  } else {
    int i = (b - 512) * 256 + t, j = i >> 8, k = i & 255;  // j<128
    w1t[j * 256 + k] = f2b(W1[k * 128 + j]);
  }
}

// ---------------- feat = h @ W + fused el/er (r10 passing version) ---------
__global__ __launch_bounds__(512, 6)
void k_gemm(const float* __restrict__ h,
            const unsigned short* __restrict__ wta,
            const unsigned short* __restrict__ wtb,
            const float* __restrict__ ala, const float* __restrict__ ara,
            const float* __restrict__ alb, const float* __restrict__ arb,
            unsigned short* __restrict__ fa, unsigned short* __restrict__ fb,
            float* __restrict__ ela, float* __restrict__ era,
            float* __restrict__ elb, float* __restrict__ erb) {
  __shared__ us8 la[64 * 8];                   // 8KB
  __shared__ us8 lbb[256 * 8];                 // 32KB
  const int z = blockIdx.y;
  const unsigned short* wt = z ? wtb : wta;
  unsigned short* f = z ? fb : fa;
  const float* al = z ? alb : ala;
  const float* ar = z ? arb : ara;
  float* el = z ? elb : ela;
  float* er = z ? erb : era;
  const int m0 = blockIdx.x * 64;
  const int t = threadIdx.x;
  const int lane = t & 63;
  const int wave = t >> 6;                     // 0..7 == head
  const int col = lane & 15;
  const int quad = lane >> 4;
  const int nw = wave * 32;                    // this wave's 32 cols
  f32x4 acc[4][2];
#pragma unroll
  for (int i = 0; i < 4; ++i)
#pragma unroll
    for (int j = 0; j < 2; ++j) acc[i][j] = (f32x4){0.f, 0.f, 0.f, 0.f};

  for (int ks = 0; ks < 4; ++ks) {
    const int k0 = ks * 64;
    __syncthreads();
    // stage A: 64 rows x 64 k, fp32 -> bf16. 1024 8B-units, 2 iters.
#pragma unroll
    for (int i = 0; i < 2; ++i) {
      int idx = i * 512 + t;
      int r = idx >> 4, g = (idx >> 1) & 7, half = idx & 1;
      int gr = m0 + r;
      f32x4 v = {0.f, 0.f, 0.f, 0.f};
      if (gr < kN) v = *(const f32x4*)(h + (size_t)gr * 256 + k0 + g * 8 + half * 4);
      us4 o;
      o.x = f2b(v.x); o.y = f2b(v.y); o.z = f2b(v.z); o.w = f2b(v.w);
      *(us4*)((unsigned short*)&la[r * 8 + (g ^ (r & 7))] + half * 4) = o;
    }
    // stage B: 256 rows x 64 k bf16. 2048 16B-units, 4 iters.
#pragma unroll
    for (int i = 0; i < 4; ++i) {
      int idx = i * 512 + t;
      int r = idx >> 3, g = idx & 7;
      lbb[r * 8 + (g ^ (r & 7))] = *(const us8*)(wt + r * 256 + k0 + g * 8);
    }
    __syncthreads();
#pragma unroll
    for (int k32 = 0; k32 < 64; k32 += 32) {
      const int cg = (k32 >> 3) + quad;
      bf16x8 af[4], bf[2];
#pragma unroll
      for (int s = 0; s < 4; ++s) {
        int arow = s * 16 + col;
        af[s] = (bf16x8)la[arow * 8 + (cg ^ (arow & 7))];
      }
#pragma unroll
      for (int j = 0; j < 2; ++j) {
        int brow = nw + j * 16 + col;
        bf[j] = (bf16x8)lbb[brow * 8 + (cg ^ (brow & 7))];
      }
#pragma unroll
      for (int i = 0; i < 4; ++i)
#pragma unroll
        for (int j = 0; j < 2; ++j)
          acc[i][j] = __builtin_amdgcn_mfma_f32_16x16x32_bf16(af[i], bf[j],
                                                              acc[i][j], 0, 0, 0);
    }
  }
  // epilogue 1: feat store (C row = quad*4+reg, col = lane&15)
#pragma unroll
  for (int i = 0; i < 4; ++i) {
#pragma unroll
    for (int r = 0; r < 4; ++r) {
      int row = m0 + i * 16 + quad * 4 + r;
      if (row < kN) {
#pragma unroll
        for (int j = 0; j < 2; ++j)
          f[(size_t)row * 256 + nw + j * 16 + col] = f2b(acc[i][j][r]);
      }
    }
  }
  // epilogue 2: el/er for this wave's single head (cols nw..nw+31)
  float alv[2], arv[2];
#pragma unroll
  for (int j = 0; j < 2; ++j) {
    alv[j] = al[nw + j * 16 + col];
    arv[j] = ar[nw + j * 16 + col];
  }
#pragma unroll
  for (int i = 0; i < 4; ++i) {
#pragma unroll
    for (int r = 0; r < 4; ++r) {
      float pl = acc[i][0][r] * alv[0] + acc[i][1][r] * alv[1];
      float pr = acc[i][0][r] * arv[0] + acc[i][1][r] * arv[1];
#pragma unroll
      for (int off = 1; off < 16; off <<= 1) {
        pl += __shfl_xor(pl, off);
        pr += __shfl_xor(pr, off);
      }
      int row = m0 + i * 16 + quad * 4 + r;
      if (col == 0 && row < kN) {
        el[row * 8 + wave] = pl;
        er[row * 8 + wave] = pr;
      }
    }
  }
}

// ---------------- CSR build via radix partition ----------------------------
__global__ __launch_bounds__(256)
void k_part(const int* __restrict__ sa, const int* __restrict__ da,
            const int* __restrict__ sb, const int* __restrict__ db,
            int* __restrict__ cnt, unsigned* __restrict__ pay) {
  int y = blockIdx.y;
  const int* s = y ? sb : sa;
  const int* d = y ? db : da;
  unsigned* p = pay + (size_t)y * kNBUK * kCAP;
  int* cn = cnt + y * kNBUK;
  __shared__ unsigned stash[6400];              // 25.6KB
  __shared__ int h[kNBUK];
  int t = threadIdx.x;
  if (t < kNBUK) h[t] = 0;
  __syncthreads();
  int e0 = blockIdx.x * 6400;
#pragma unroll 5
  for (int it = 0; it < 25; ++it) {
    int e = e0 + it * 256 + t;
    int sv = s[e], dv = d[e];
    int b = dv >> 9;
    stash[it * 256 + t] = (unsigned)sv | ((unsigned)(dv & 511) << 16) |
                          ((unsigned)b << 25);
    atomicAdd(&h[b], 1);
  }
  __syncthreads();
  if (t < kNBUK) h[t] = atomicAdd(&cn[t], h[t]);  // h becomes block's cursor
  __syncthreads();
#pragma unroll 5
  for (int it = 0; it < 25; ++it) {
    unsigned w = stash[it * 256 + t];
    int b = w >> 25;
    int slot = atomicAdd(&h[b], 1);
    p[b * kCAP + slot] = w & 0x1FFFFFFu;
  }
}

// k_bscan: exclusive scan of 2x98 bucket counts -> global es/rp bases.
__global__ __launch_bounds__(256)
void k_bscan(const int* __restrict__ cnt, int* __restrict__ bbase,
             int* __restrict__ rpa, int* __restrict__ rpb) {
  __shared__ int buf[2][128];
  int t = threadIdx.x;
  int y = t >> 7, i = t & 127;
  int x = (i < kNBUK) ? cnt[y * kNBUK + i] : 0;
  buf[y][i] = x;
  __syncthreads();
  for (int off = 1; off < 128; off <<= 1) {
    int v = (i >= off) ? buf[y][i - off] : 0;
    __syncthreads();
    buf[y][i] += v;
    __syncthreads();
  }
  if (i < kNBUK) bbase[y * kNBUK + i] = buf[y][i] - x;
  if (t == 0) { rpa[kN] = kE; rpb[kN] = kE; }
}

// k_bucket: one block per (bucket, graph). LDS histogram + pair scan ->
// writes rp segment AND scatters es via LDS cursor atomics.
__global__ __launch_bounds__(256)
void k_bucket(const int* __restrict__ cnt, const int* __restrict__ bbase,
              const unsigned* __restrict__ pay,
              int* __restrict__ rpa, int* __restrict__ rpb,
              int* __restrict__ esa, int* __restrict__ esb) {
  int b = blockIdx.x, y = blockIdx.y;
  int* rp = y ? rpb : rpa;
  int* es = y ? esb : esa;
  const unsigned* p = pay + ((size_t)y * kNBUK + b) * kCAP;
  int c = cnt[y * kNBUK + b];
  int base = bbase[y * kNBUK + b];
  __shared__ unsigned pl[kCAP];                 // 36.9KB
  __shared__ int h[512];
  __shared__ int buf[256];
  int t = threadIdx.x;
  h[t] = 0; h[t + 256] = 0;
  __syncthreads();
  for (int i = t; i < c; i += 256) {
    unsigned w = p[i];
    pl[i] = w;
    atomicAdd(&h[(w >> 16) & 511], 1);
  }
  __syncthreads();
  int a = h[2 * t], b1 = h[2 * t + 1];
  int s2 = a + b1;
  buf[t] = s2;
  __syncthreads();
  for (int off = 1; off < 256; off <<= 1) {
    int v = (t >= off) ? buf[t - off] : 0;
    __syncthreads();
    buf[t] += v;
    __syncthreads();
  }
  int ex = buf[t] - s2;                         // exclusive pair base
  int g0 = b * 512 + 2 * t;
  if (g0 < kN) rp[g0] = base + ex;
  if (g0 + 1 < kN) rp[g0 + 1] = base + ex + a;
  h[2 * t] = ex;                                // h becomes local cursors
  h[2 * t + 1] = ex + a;
  __syncthreads();
  for (int i = t; i < c; i += 256) {
    unsigned w = pl[i];
    int slot = atomicAdd(&h[(w >> 16) & 511], 1);
    es[base + slot] = (int)(w & 0xFFFFu);
  }
}

// ---------------- GAT aggregate (round-3 proven structure, per-graph) ------
__global__ __launch_bounds__(256)
void k_agg(const int* __restrict__ rp, const int* __restrict__ es,
           const float* __restrict__ el, const float* __restrict__ er,
           const unsigned short* __restrict__ feat,
           const float* __restrict__ bias,
           float* __restrict__ za, unsigned short* __restrict__ zb,
           int y) {
  __shared__ float wls[4][512];                // 64 edges x 8 heads per wave
  __shared__ int sls[4][64];
  int nb = blockIdx.x;
  int lane = threadIdx.x & 63;
  int wave = threadIdx.x >> 6;
  int n = nb * 4 + wave;
  int hh = lane >> 3;                          // phase1 edge-slot
  int h = lane & 7;                            // phase1 head
  int half = lane >> 5;                        // phase2: which edge of pair
  int l5 = lane & 31;
  int h2 = l5 >> 2;                            // phase2 head (dims l5*8..+7)
  unsigned idx16 = (unsigned)l5 * 16u;         // byte offset in feat row
  float erh = er[n * 8 + h];
  int e0 = rp[n], e1 = rp[n + 1];
  float dsum = 0.f;
  float a0 = 0.f, a1 = 0.f, a2 = 0.f, a3 = 0.f;
  float a4 = 0.f, a5 = 0.f, a6 = 0.f, a7 = 0.f;

  for (int cb = e0; cb < e1; cb += 64) {
    int cnt = e1 - cb;
    if (cnt > 64) cnt = 64;
    // phase 1: weights -> LDS, 8 edges/iter, no lane redundancy
    for (int it = 0; it * 8 < cnt; ++it) {
      int j = it * 8 + hh;
      if (j < cnt) {
        int s = es[cb + j];
        float ev = *(const float*)((const char*)el + ((unsigned)s << 5) +
                                   ((unsigned)h << 2)) + erh;
        ev = fmaxf(ev, 0.2f * ev);             // LeakyReLU(0.2)
        float w = __expf(ev);
        wls[wave][it * 64 + lane] = w;         // == [j*8 + h]
        if (h == 0) sls[wave][j] = s;
        dsum += w;
      }
    }
    // phase 2: 2 edges/instr, 16B/lane (same-wave LDS dep, no barrier)
    int j = 0;
    for (; j + 7 < cnt; j += 8) {
#pragma unroll
      for (int p = 0; p < 4; ++p) {
        int jj = j + 2 * p + half;
        int s = sls[wave][jj];
        float w = wls[wave][jj * 8 + h2];
        us8 fv = *(const us8*)((const char*)feat + (((unsigned)s << 9) + idx16));
        a0 += w * b2f(fv[0]);
        a1 += w * b2f(fv[1]);
        a2 += w * b2f(fv[2]);
        a3 += w * b2f(fv[3]);
        a4 += w * b2f(fv[4]);
        a5 += w * b2f(fv[5]);
        a6 += w * b2f(fv[6]);
        a7 += w * b2f(fv[7]);
      }
    }
    if (j < cnt) {
#pragma unroll
      for (int p = 0; p < 4; ++p) {
        int jj = j + 2 * p + half;
        bool v = jj < cnt;
        int jc = v ? jj : j;
        int s = sls[wave][jc];
        float w = v ? wls[wave][jc * 8 + h2] : 0.f;
        us8 fv = *(const us8*)((const char*)feat + (((unsigned)s << 9) + idx16));
        a0 += w * b2f(fv[0]);
        a1 += w * b2f(fv[1]);
        a2 += w * b2f(fv[2]);
        a3 += w * b2f(fv[3]);
        a4 += w * b2f(fv[4]);
        a5 += w * b2f(fv[5]);
        a6 += w * b2f(fv[6]);
        a7 += w * b2f(fv[7]);
      }
    }
  }
  // combine halves (each half holds alternating edges' partials)
  a0 += __shfl_xor(a0, 32); a1 += __shfl_xor(a1, 32);
  a2 += __shfl_xor(a2, 32); a3 += __shfl_xor(a3, 32);
  a4 += __shfl_xor(a4, 32); a5 += __shfl_xor(a5, 32);
  a6 += __shfl_xor(a6, 32); a7 += __shfl_xor(a7, 32);
  // denom: reduce over edge-slot bits; lane i holds head i&7 total
  dsum += __shfl_xor(dsum, 8);
  dsum += __shfl_xor(dsum, 16);
  dsum += __shfl_xor(dsum, 32);
  float dh = __shfl(dsum, h2);                 // this lane's head total
  float inv = __builtin_amdgcn_rcpf(dh > 0.f ? dh : 1.f);
  f32x4 blo = *(const f32x4*)(bias + l5 * 8);
  f32x4 bhi = *(const f32x4*)(bias + l5 * 8 + 4);
  float r0 = a0 * inv + blo.x;
  float r1 = a1 * inv + blo.y;
  float r2 = a2 * inv + blo.z;
  float r3 = a3 * inv + blo.w;
  float r4 = a4 * inv + bhi.x;
  float r5 = a5 * inv + bhi.y;
  float r6 = a6 * inv + bhi.z;
  float r7 = a7 * inv + bhi.w;
  r0 = r0 > 0.f ? r0 : __expf(r0) - 1.f;       // ELU (no libm)
  r1 = r1 > 0.f ? r1 : __expf(r1) - 1.f;
  r2 = r2 > 0.f ? r2 : __expf(r2) - 1.f;
  r3 = r3 > 0.f ? r3 : __expf(r3) - 1.f;
  r4 = r4 > 0.f ? r4 : __expf(r4) - 1.f;
  r5 = r5 > 0.f ? r5 : __expf(r5) - 1.f;
  r6 = r6 > 0.f ? r6 : __expf(r6) - 1.f;
  r7 = r7 > 0.f ? r7 : __expf(r7) - 1.f;
  f32x4 lo = {r0, r1, r2, r3};
  f32x4 hi = {r4, r5, r6, r7};
  f32x4 ov = half ? hi : lo;
  if (y == 0) {
    *(f32x4*)((char*)za + (size_t)n * 1024 + l5 * 32 + half * 16) = ov;
  } else {
    us4 o;
    o.x = f2b(ov.x); o.y = f2b(ov.y); o.z = f2b(ov.z); o.w = f2b(ov.w);
    *(us4*)((char*)zb + (size_t)n * 512 + l5 * 16 + half * 8) = o;
  }
}

// ---------------- semantic scores via MFMA ---------------------------------
// r13 post-mortem: no spill, but still 123us vs ~20us roofline — structural
// latency: 3 grid-stride tiles/wave x 8 SERIAL load->cvt->MFMA steps with
// only ~4 waves/SIMD. Fix: (1) ONE tile per wave (grid 1563x2 -> 6252
// waves, 3x blocks); (2) all 8 K-step A-loads issued upfront into afr[8]
// (statically indexed -> registers) so the tile has ~1 latency exposure;
// (3) per-block LDS partial sums -> 1-2 global atomics per block (handles
// the za/zb boundary block). No early returns (barrier-uniform).
__global__ __launch_bounds__(256)
void k_sem(const float* __restrict__ za,
           const unsigned short* __restrict__ zb,
           const unsigned short* __restrict__ w1t,
           const float* __restrict__ b1,
           const float* __restrict__ W2,
           float* __restrict__ wacc) {
  __shared__ us8 w1l[2048];                     // 64 rows x 32 chunks, 32KB
  __shared__ float psum[2];
  int t = threadIdx.x;
  int jbase = blockIdx.y * 64;                  // this block's j-half
  if (t < 2) psum[t] = 0.f;
  for (int i = t; i < 2048; i += 256) {
    int j = i >> 5, c = i & 31;                 // j local 0..63
    w1l[j * 32 + (c ^ (j & 7))] = ((const us8*)w1t)[(jbase + j) * 32 + c];
  }
  __syncthreads();
  int lane = t & 63, wave = t >> 6;
  int col = lane & 15, quad = lane >> 4;
  float b1v[4], w2v[4];
#pragma unroll
  for (int tt = 0; tt < 4; ++tt) {
    b1v[tt] = b1[jbase + tt * 16 + col];
    w2v[tt] = W2[jbase + tt * 16 + col];
  }
  int gt = blockIdx.x * 4 + wave;               // one tile per wave
  bool valid = gt < 6250;
  // load all 8 A fragments upfront (single latency exposure)
  bf16x8 afr[8];
  if (valid && gt < 3125) {
    const float* ap = za + (size_t)gt * 4096 + col * 256 + quad * 8;
#pragma unroll
    for (int ks = 0; ks < 8; ++ks) {
      f32x4 a0 = *(const f32x4*)(ap + ks * 32);
      f32x4 a1 = *(const f32x4*)(ap + ks * 32 + 4);
      afr[ks][0] = (short)f2b(a0.x); afr[ks][1] = (short)f2b(a0.y);
      afr[ks][2] = (short)f2b(a0.z); afr[ks][3] = (short)f2b(a0.w);
      afr[ks][4] = (short)f2b(a1.x); afr[ks][5] = (short)f2b(a1.y);
      afr[ks][6] = (short)f2b(a1.z); afr[ks][7] = (short)f2b(a1.w);
    }
  } else if (valid) {
    const unsigned short* ap = zb + (size_t)(gt - 3125) * 4096 + col * 256 +
                               quad * 8;
#pragma unroll
    for (int ks = 0; ks < 8; ++ks)
      afr[ks] = *(const bf16x8*)(ap + ks * 32);
  } else {
#pragma unroll
    for (int ks = 0; ks < 8; ++ks) afr[ks] = (bf16x8)(short)0;
  }
  f32x4 acc[4];
#pragma unroll
  for (int tt = 0; tt < 4; ++tt) acc[tt] = (f32x4){0.f, 0.f, 0.f, 0.f};
#pragma unroll
  for (int ks = 0; ks < 8; ++ks) {
    int c = ks * 4 + quad;
#pragma unroll
    for (int tt = 0; tt < 4; ++tt) {
      int j = tt * 16 + col;                    // local j
      bf16x8 b = (bf16x8)w1l[j * 32 + (c ^ (j & 7))];
      acc[tt] = __builtin_amdgcn_mfma_f32_16x16x32_bf16(afr[ks], b, acc[tt],
                                                        0, 0, 0);
    }
  }
  float tot = 0.f;
#pragma unroll
  for (int tt = 0; tt < 4; ++tt)
#pragma unroll
    for (int r = 0; r < 4; ++r) {
      float x = acc[tt][r] + b1v[tt];
      x = fminf(fmaxf(x, -10.f), 10.f);         // clamp for exp overflow
      float ex = __expf(2.f * x);               // tanh = (e^2x-1)/(e^2x+1)
      tot += (ex - 1.f) * __builtin_amdgcn_rcpf(ex + 1.f) * w2v[tt];
    }
#pragma unroll
  for (int off = 1; off < 64; off <<= 1) tot += __shfl_xor(tot, off);
  if (lane == 0 && valid)
    atomicAdd(&psum[gt < 3125 ? 0 : 1], tot);   // LDS atomic, cheap
  __syncthreads();
  if (t == 0 && psum[0] != 0.f) atomicAdd(&wacc[0], psum[0]);
  if (t == 1 && psum[1] != 0.f) atomicAdd(&wacc[1], psum[1]);
}

// ---------------- beta softmax + combine (in-place over za==out) -----------
__global__ __launch_bounds__(256)
void k_combine(const float* __restrict__ za,
               const unsigned short* __restrict__ zb,
               const float* __restrict__ wacc,
               float* __restrict__ out) {
  int i = blockIdx.x * 256 + threadIdx.x;       // 3.2M groups of 4
  float wa = wacc[0] * (1.f / kN), wb = wacc[1] * (1.f / kN);
  float mx = fmaxf(wa, wb);
  float ea = __expf(wa - mx), eb = __expf(wb - mx);
  float inv = __builtin_amdgcn_rcpf(ea + eb);
  float ba = ea * inv, bb = eb * inv;
  f32x4 x = ((const f32x4*)za)[i];
  us4 yv = ((const us4*)zb)[i];
  f32x4 o;
#pragma unroll
  for (int j = 0; j < 4; ++j)
    o[j] = ba * x[j] + bb * b2f(yv[j]);
  ((f32x4*)out)[i] = o;
}

extern "C" void kernel_launch(void* const* d_in, const int* in_sizes, int n_in,
                              void* d_out, int out_size, void* d_ws, size_t ws_size,
                              hipStream_t stream) {
  const float* hin = (const float*)d_in[0];
  const int* src_a = (const int*)d_in[1];
  const int* dst_a = (const int*)d_in[2];
  const int* src_b = (const int*)d_in[3];
  const int* dst_b = (const int*)d_in[4];
  const float* W_a = (const float*)d_in[5];
  const float* al_a = (const float*)d_in[6];
  const float* ar_a = (const float*)d_in[7];
  const float* bias_a = (const float*)d_in[8];
  const float* W_b = (const float*)d_in[9];
  const float* al_b = (const float*)d_in[10];
  const float* ar_b = (const float*)d_in[11];
  const float* bias_b = (const float*)d_in[12];
  const float* sW1 = (const float*)d_in[13];
  const float* sb1 = (const float*)d_in[14];
  const float* sW2 = (const float*)d_in[15];
  float* out = (float*)d_out;

  char* wsb = (char*)d_ws;
  size_t off = 0;
  auto alloc = [&](size_t bytes) -> char* {
    char* p = wsb + off;
    off = (off + bytes + 511) & ~(size_t)511;
    return p;
  };
  // Footprint ~98 MB.
  unsigned short* feat_a = (unsigned short*)alloc((size_t)kN * 256 * 2); // 25.6MB
  unsigned short* feat_b = (unsigned short*)alloc((size_t)kN * 256 * 2); // 25.6MB
  unsigned short* z_b    = (unsigned short*)alloc((size_t)kN * 256 * 2); // 25.6MB
  float* el_a = (float*)alloc((size_t)kN * 8 * 4);
  float* er_a = (float*)alloc((size_t)kN * 8 * 4);
  float* el_b = (float*)alloc((size_t)kN * 8 * 4);
  float* er_b = (float*)alloc((size_t)kN * 8 * 4);
  unsigned short* wt_a = (unsigned short*)alloc(65536 * 2);
  unsigned short* wt_b = (unsigned short*)alloc(65536 * 2);
  unsigned short* w1t  = (unsigned short*)alloc(32768 * 2);
  int* rp_a = (int*)alloc((size_t)(kN + 1) * 4);
  int* rp_b = (int*)alloc((size_t)(kN + 1) * 4);
  int* es_a = (int*)alloc((size_t)kE * 4);
  int* es_b = (int*)alloc((size_t)kE * 4);
  unsigned* pay = (unsigned*)alloc((size_t)2 * kNBUK * kCAP * 4);  // 7.2MB
  int* cnt = (int*)alloc((size_t)2 * kNBUK * 4);
  int* bbase = (int*)alloc((size_t)2 * kNBUK * 4);
  float* wacc = (float*)alloc(2 * 4);

  hipMemsetAsync(cnt, 0, (size_t)2 * kNBUK * 4, stream);
  hipMemsetAsync(wacc, 0, 8, stream);

  k_prep<<<640, 256, 0, stream>>>(W_a, W_b, sW1, wt_a, wt_b, w1t);
  k_part<<<dim3(125, 2), 256, 0, stream>>>(src_a, dst_a, src_b, dst_b, cnt, pay);
  k_bscan<<<1, 256, 0, stream>>>(cnt, bbase, rp_a, rp_b);
  k_bucket<<<dim3(kNBUK, 2), 256, 0, stream>>>(cnt, bbase, pay,
                                               rp_a, rp_b, es_a, es_b);
  k_gemm<<<dim3(782, 2), 512, 0, stream>>>(hin, wt_a, wt_b,
                                           al_a, ar_a, al_b, ar_b,
                                           feat_a, feat_b,
                                           el_a, er_a, el_b, er_b);
  k_agg<<<12500, 256, 0, stream>>>(rp_a, es_a, el_a, er_a, feat_a, bias_a,
                                   out, z_b, 0);
  k_agg<<<12500, 256, 0, stream>>>(rp_b, es_b, el_b, er_b, feat_b, bias_b,
                                   out, z_b, 1);
  k_sem<<<dim3(1563, 2), 256, 0, stream>>>(out, z_b, w1t, sb1, sW2, wacc);
  k_combine<<<12500, 256, 0, stream>>>(out, z_b, wacc, out);
}

// Round 15
// 423.736 us; speedup vs baseline: 1.3906x; 1.0019x over previous
//
#include <hip/hip_runtime.h>
#include <math.h>

typedef __attribute__((ext_vector_type(8))) short bf16x8;
typedef __attribute__((ext_vector_type(4))) float f32x4;
typedef __attribute__((ext_vector_type(4))) unsigned short us4;
typedef __attribute__((ext_vector_type(8))) unsigned short us8;

static constexpr int kN  = 50000;
static constexpr int kE  = 800000;
static constexpr int kNBUK = 98;     // ceil(50000/512), bucket = dst>>9
static constexpr int kCAP  = 9216;   // per-bucket payload cap (mean 8163 + 11.6 sigma)

__device__ __forceinline__ float b2f(unsigned short u) {
  union { unsigned u; float f; } x; x.u = ((unsigned)u) << 16; return x.f;
}
__device__ __forceinline__ unsigned short f2b(float f) {
  union { float f; unsigned u; } x; x.f = f;
  unsigned u = x.u;
  unsigned r = (u + 0x7fffu + ((u >> 16) & 1u)) >> 16;
  return (unsigned short)r;
}

// ---------------- fused prep: Wt_a, Wt_b (bf16 [256][256]), W1T (bf16 [128][256])
__global__ __launch_bounds__(256)
void k_prep(const float* __restrict__ Wa, const float* __restrict__ Wb,
            const float* __restrict__ W1,
            unsigned short* __restrict__ wta, unsigned short* __restrict__ wtb,
            unsigned short* __restrict__ w1t) {
  int b = blockIdx.x, t = threadIdx.x;
  if (b < 256) {
    int i = b * 256 + t, j = i >> 8, k = i & 255;
    wta[j * 256 + k] = f2b(Wa[k * 256 + j]);
  } else if (b < 512) {
    int i = (b - 256) * 256 + t, j = i >> 8, k = i & 255;
    wtb[j * 256 + k] = f2b(Wb[k * 256 + j]);
  } else {
    int i = (b - 512) * 256 + t, j = i >> 8, k = i & 255;  // j<128
    w1t[j * 256 + k] = f2b(W1[k * 128 + j]);
  }
}

// ---------------- feat = h @ W + fused el/er, reg-prefetch pipeline --------
// r14: 69us, MfmaUtil 7%, nothing saturated -> per-K-step loads issued after
// barrier-2 and consumed immediately = full HBM latency in critical section.
// Fix (T14 async-stage): prologue loads ks=0 to regs; per step:
//   barrier -> regs->LDS (+f2b) -> barrier -> ISSUE ks+1 loads -> MFMA.
// Loads overlap the whole compute phase. +24 VGPR (40->~64, cap 85, no spill).
__global__ __launch_bounds__(512, 6)
void k_gemm(const float* __restrict__ h,
            const unsigned short* __restrict__ wta,
            const unsigned short* __restrict__ wtb,
            const float* __restrict__ ala, const float* __restrict__ ara,
            const float* __restrict__ alb, const float* __restrict__ arb,
            unsigned short* __restrict__ fa, unsigned short* __restrict__ fb,
            float* __restrict__ ela, float* __restrict__ era,
            float* __restrict__ elb, float* __restrict__ erb) {
  __shared__ us8 la[64 * 8];                   // 8KB
  __shared__ us8 lbb[256 * 8];                 // 32KB
  const int z = blockIdx.y;
  const unsigned short* wt = z ? wtb : wta;
  unsigned short* f = z ? fb : fa;
  const float* al = z ? alb : ala;
  const float* ar = z ? arb : ara;
  float* el = z ? elb : ela;
  float* er = z ? erb : era;
  const int m0 = blockIdx.x * 64;
  const int t = threadIdx.x;
  const int lane = t & 63;
  const int wave = t >> 6;                     // 0..7 == head
  const int col = lane & 15;
  const int quad = lane >> 4;
  const int nw = wave * 32;                    // this wave's 32 cols
  // per-thread staging unit indices (constant over K-steps)
  int ar_[2], ag_[2], ah_[2]; bool av_[2];
#pragma unroll
  for (int i = 0; i < 2; ++i) {
    int idx = i * 512 + t;
    ar_[i] = idx >> 4; ag_[i] = (idx >> 1) & 7; ah_[i] = idx & 1;
    av_[i] = (m0 + ar_[i]) < kN;
  }
  int br_[4], bg_[4];
#pragma unroll
  for (int i = 0; i < 4; ++i) {
    int idx = i * 512 + t;
    br_[i] = idx >> 3; bg_[i] = idx & 7;
  }
  f32x4 acc[4][2];
#pragma unroll
  for (int i = 0; i < 4; ++i)
#pragma unroll
    for (int j = 0; j < 2; ++j) acc[i][j] = (f32x4){0.f, 0.f, 0.f, 0.f};

  // prologue: load K-step 0 into registers
  f32x4 pa[2]; us8 pb[4];
#pragma unroll
  for (int i = 0; i < 2; ++i)
    pa[i] = av_[i] ? *(const f32x4*)(h + (size_t)(m0 + ar_[i]) * 256 +
                                     ag_[i] * 8 + ah_[i] * 4)
                   : (f32x4){0.f, 0.f, 0.f, 0.f};
#pragma unroll
  for (int i = 0; i < 4; ++i)
    pb[i] = *(const us8*)(wt + br_[i] * 256 + bg_[i] * 8);

  for (int ks = 0; ks < 4; ++ks) {
    __syncthreads();                           // prev compute done, LDS free
    // write staged regs -> LDS (fp32 -> bf16 for A)
#pragma unroll
    for (int i = 0; i < 2; ++i) {
      us4 o;
      o.x = f2b(pa[i].x); o.y = f2b(pa[i].y);
      o.z = f2b(pa[i].z); o.w = f2b(pa[i].w);
      *(us4*)((unsigned short*)&la[ar_[i] * 8 + (ag_[i] ^ (ar_[i] & 7))] +
              ah_[i] * 4) = o;
    }
#pragma unroll
    for (int i = 0; i < 4; ++i)
      lbb[br_[i] * 8 + (bg_[i] ^ (br_[i] & 7))] = pb[i];
    __syncthreads();                           // LDS ready
    if (ks < 3) {                              // issue next-step loads now;
      const int k0n = (ks + 1) * 64;           // they fly during the MFMAs
#pragma unroll
      for (int i = 0; i < 2; ++i)
        pa[i] = av_[i] ? *(const f32x4*)(h + (size_t)(m0 + ar_[i]) * 256 +
                                         k0n + ag_[i] * 8 + ah_[i] * 4)
                       : (f32x4){0.f, 0.f, 0.f, 0.f};
#pragma unroll
      for (int i = 0; i < 4; ++i)
        pb[i] = *(const us8*)(wt + br_[i] * 256 + k0n + bg_[i] * 8);
    }
#pragma unroll
    for (int k32 = 0; k32 < 64; k32 += 32) {
      const int cg = (k32 >> 3) + quad;
      bf16x8 af[4], bf[2];
#pragma unroll
      for (int s = 0; s < 4; ++s) {
        int arow = s * 16 + col;
        af[s] = (bf16x8)la[arow * 8 + (cg ^ (arow & 7))];
      }
#pragma unroll
      for (int j = 0; j < 2; ++j) {
        int brow = nw + j * 16 + col;
        bf[j] = (bf16x8)lbb[brow * 8 + (cg ^ (brow & 7))];
      }
#pragma unroll
      for (int i = 0; i < 4; ++i)
#pragma unroll
        for (int j = 0; j < 2; ++j)
          acc[i][j] = __builtin_amdgcn_mfma_f32_16x16x32_bf16(af[i], bf[j],
                                                              acc[i][j], 0, 0, 0);
    }
  }
  // epilogue 1: feat store (C row = quad*4+reg, col = lane&15)
#pragma unroll
  for (int i = 0; i < 4; ++i) {
#pragma unroll
    for (int r = 0; r < 4; ++r) {
      int row = m0 + i * 16 + quad * 4 + r;
      if (row < kN) {
#pragma unroll
        for (int j = 0; j < 2; ++j)
          f[(size_t)row * 256 + nw + j * 16 + col] = f2b(acc[i][j][r]);
      }
    }
  }
  // epilogue 2: el/er for this wave's single head (cols nw..nw+31)
  float alv[2], arv[2];
#pragma unroll
  for (int j = 0; j < 2; ++j) {
    alv[j] = al[nw + j * 16 + col];
    arv[j] = ar[nw + j * 16 + col];
  }
#pragma unroll
  for (int i = 0; i < 4; ++i) {
#pragma unroll
    for (int r = 0; r < 4; ++r) {
      float pl = acc[i][0][r] * alv[0] + acc[i][1][r] * alv[1];
      float pr = acc[i][0][r] * arv[0] + acc[i][1][r] * arv[1];
#pragma unroll
      for (int off = 1; off < 16; off <<= 1) {
        pl += __shfl_xor(pl, off);
        pr += __shfl_xor(pr, off);
      }
      int row = m0 + i * 16 + quad * 4 + r;
      if (col == 0 && row < kN) {
        el[row * 8 + wave] = pl;
        er[row * 8 + wave] = pr;
      }
    }
  }
}

// ---------------- CSR build via radix partition ----------------------------
__global__ __launch_bounds__(256)
void k_part(const int* __restrict__ sa, const int* __restrict__ da,
            const int* __restrict__ sb, const int* __restrict__ db,
            int* __restrict__ cnt, unsigned* __restrict__ pay) {
  int y = blockIdx.y;
  const int* s = y ? sb : sa;
  const int* d = y ? db : da;
  unsigned* p = pay + (size_t)y * kNBUK * kCAP;
  int* cn = cnt + y * kNBUK;
  __shared__ unsigned stash[6400];              // 25.6KB
  __shared__ int h[kNBUK];
  int t = threadIdx.x;
  if (t < kNBUK) h[t] = 0;
  __syncthreads();
  int e0 = blockIdx.x * 6400;
#pragma unroll 5
  for (int it = 0; it < 25; ++it) {
    int e = e0 + it * 256 + t;
    int sv = s[e], dv = d[e];
    int b = dv >> 9;
    stash[it * 256 + t] = (unsigned)sv | ((unsigned)(dv & 511) << 16) |
                          ((unsigned)b << 25);
    atomicAdd(&h[b], 1);
  }
  __syncthreads();
  if (t < kNBUK) h[t] = atomicAdd(&cn[t], h[t]);  // h becomes block's cursor
  __syncthreads();
#pragma unroll 5
  for (int it = 0; it < 25; ++it) {
    unsigned w = stash[it * 256 + t];
    int b = w >> 25;
    int slot = atomicAdd(&h[b], 1);
    p[b * kCAP + slot] = w & 0x1FFFFFFu;
  }
}

// k_bscan: exclusive scan of 2x98 bucket counts -> global es/rp bases.
__global__ __launch_bounds__(256)
void k_bscan(const int* __restrict__ cnt, int* __restrict__ bbase,
             int* __restrict__ rpa, int* __restrict__ rpb) {
  __shared__ int buf[2][128];
  int t = threadIdx.x;
  int y = t >> 7, i = t & 127;
  int x = (i < kNBUK) ? cnt[y * kNBUK + i] : 0;
  buf[y][i] = x;
  __syncthreads();
  for (int off = 1; off < 128; off <<= 1) {
    int v = (i >= off) ? buf[y][i - off] : 0;
    __syncthreads();
    buf[y][i] += v;
    __syncthreads();
  }
  if (i < kNBUK) bbase[y * kNBUK + i] = buf[y][i] - x;
  if (t == 0) { rpa[kN] = kE; rpb[kN] = kE; }
}

// k_bucket: one block per (bucket, graph). LDS histogram + pair scan ->
// writes rp segment AND scatters es via LDS cursor atomics.
__global__ __launch_bounds__(256)
void k_bucket(const int* __restrict__ cnt, const int* __restrict__ bbase,
              const unsigned* __restrict__ pay,
              int* __restrict__ rpa, int* __restrict__ rpb,
              int* __restrict__ esa, int* __restrict__ esb) {
  int b = blockIdx.x, y = blockIdx.y;
  int* rp = y ? rpb : rpa;
  int* es = y ? esb : esa;
  const unsigned* p = pay + ((size_t)y * kNBUK + b) * kCAP;
  int c = cnt[y * kNBUK + b];
  int base = bbase[y * kNBUK + b];
  __shared__ unsigned pl[kCAP];                 // 36.9KB
  __shared__ int h[512];
  __shared__ int buf[256];
  int t = threadIdx.x;
  h[t] = 0; h[t + 256] = 0;
  __syncthreads();
  for (int i = t; i < c; i += 256) {
    unsigned w = p[i];
    pl[i] = w;
    atomicAdd(&h[(w >> 16) & 511], 1);
  }
  __syncthreads();
  int a = h[2 * t], b1 = h[2 * t + 1];
  int s2 = a + b1;
  buf[t] = s2;
  __syncthreads();
  for (int off = 1; off < 256; off <<= 1) {
    int v = (t >= off) ? buf[t - off] : 0;
    __syncthreads();
    buf[t] += v;
    __syncthreads();
  }
  int ex = buf[t] - s2;                         // exclusive pair base
  int g0 = b * 512 + 2 * t;
  if (g0 < kN) rp[g0] = base + ex;
  if (g0 + 1 < kN) rp[g0 + 1] = base + ex + a;
  h[2 * t] = ex;                                // h becomes local cursors
  h[2 * t + 1] = ex + a;
  __syncthreads();
  for (int i = t; i < c; i += 256) {
    unsigned w = pl[i];
    int slot = atomicAdd(&h[(w >> 16) & 511], 1);
    es[base + slot] = (int)(w & 0xFFFFu);
  }
}

// ---------------- GAT aggregate (round-3 proven, single flat dispatch) -----
// Merged back from the r7 diagnostic split: single dispatch saves ~10us and
// one launch; graph-a blocks dispatch (mostly) before graph-b.
__global__ __launch_bounds__(256)
void k_agg(const int* __restrict__ rpa, const int* __restrict__ rpb,
           const int* __restrict__ esa, const int* __restrict__ esb,
           const float* __restrict__ ela, const float* __restrict__ era,
           const float* __restrict__ elb, const float* __restrict__ erb,
           const unsigned short* __restrict__ fa,
           const unsigned short* __restrict__ fb,
           const float* __restrict__ biasa, const float* __restrict__ biasb,
           float* __restrict__ za, unsigned short* __restrict__ zb) {
  __shared__ float wls[4][512];                // 64 edges x 8 heads per wave
  __shared__ int sls[4][64];
  int bx = blockIdx.x;
  int y = bx >= 12500;
  int nb = y ? bx - 12500 : bx;
  const int* rp = y ? rpb : rpa;
  const int* es = y ? esb : esa;
  const float* el = y ? elb : ela;
  const float* er = y ? erb : era;
  const unsigned short* feat = y ? fb : fa;
  const float* bias = y ? biasb : biasa;
  int lane = threadIdx.x & 63;
  int wave = threadIdx.x >> 6;
  int n = nb * 4 + wave;
  int hh = lane >> 3;                          // phase1 edge-slot
  int h = lane & 7;                            // phase1 head
  int half = lane >> 5;                        // phase2: which edge of pair
  int l5 = lane & 31;
  int h2 = l5 >> 2;                            // phase2 head (dims l5*8..+7)
  unsigned idx16 = (unsigned)l5 * 16u;         // byte offset in feat row
  float erh = er[n * 8 + h];
  int e0 = rp[n], e1 = rp[n + 1];
  float dsum = 0.f;
  float a0 = 0.f, a1 = 0.f, a2 = 0.f, a3 = 0.f;
  float a4 = 0.f, a5 = 0.f, a6 = 0.f, a7 = 0.f;

  for (int cb = e0; cb < e1; cb += 64) {
    int cnt = e1 - cb;
    if (cnt > 64) cnt = 64;
    // phase 1: weights -> LDS, 8 edges/iter, no lane redundancy
    for (int it = 0; it * 8 < cnt; ++it) {
      int j = it * 8 + hh;
      if (j < cnt) {
        int s = es[cb + j];
        float ev = *(const float*)((const char*)el + ((unsigned)s << 5) +
                                   ((unsigned)h << 2)) + erh;
        ev = fmaxf(ev, 0.2f * ev);             // LeakyReLU(0.2)
        float w = __expf(ev);
        wls[wave][it * 64 + lane] = w;         // == [j*8 + h]
        if (h == 0) sls[wave][j] = s;
        dsum += w;
      }
    }
    // phase 2: 2 edges/instr, 16B/lane (same-wave LDS dep, no barrier)
    int j = 0;
    for (; j + 7 < cnt; j += 8) {
#pragma unroll
      for (int p = 0; p < 4; ++p) {
        int jj = j + 2 * p + half;
        int s = sls[wave][jj];
        float w = wls[wave][jj * 8 + h2];
        us8 fv = *(const us8*)((const char*)feat + (((unsigned)s << 9) + idx16));
        a0 += w * b2f(fv[0]);
        a1 += w * b2f(fv[1]);
        a2 += w * b2f(fv[2]);
        a3 += w * b2f(fv[3]);
        a4 += w * b2f(fv[4]);
        a5 += w * b2f(fv[5]);
        a6 += w * b2f(fv[6]);
        a7 += w * b2f(fv[7]);
      }
    }
    if (j < cnt) {
#pragma unroll
      for (int p = 0; p < 4; ++p) {
        int jj = j + 2 * p + half;
        bool v = jj < cnt;
        int jc = v ? jj : j;
        int s = sls[wave][jc];
        float w = v ? wls[wave][jc * 8 + h2] : 0.f;
        us8 fv = *(const us8*)((const char*)feat + (((unsigned)s << 9) + idx16));
        a0 += w * b2f(fv[0]);
        a1 += w * b2f(fv[1]);
        a2 += w * b2f(fv[2]);
        a3 += w * b2f(fv[3]);
        a4 += w * b2f(fv[4]);
        a5 += w * b2f(fv[5]);
        a6 += w * b2f(fv[6]);
        a7 += w * b2f(fv[7]);
      }
    }
  }
  // combine halves (each half holds alternating edges' partials)
  a0 += __shfl_xor(a0, 32); a1 += __shfl_xor(a1, 32);
  a2 += __shfl_xor(a2, 32); a3 += __shfl_xor(a3, 32);
  a4 += __shfl_xor(a4, 32); a5 += __shfl_xor(a5, 32);
  a6 += __shfl_xor(a6, 32); a7 += __shfl_xor(a7, 32);
  // denom: reduce over edge-slot bits; lane i holds head i&7 total
  dsum += __shfl_xor(dsum, 8);
  dsum += __shfl_xor(dsum, 16);
  dsum += __shfl_xor(dsum, 32);
  float dh = __shfl(dsum, h2);                 // this lane's head total
  float inv = __builtin_amdgcn_rcpf(dh > 0.f ? dh : 1.f);
  f32x4 blo = *(const f32x4*)(bias + l5 * 8);
  f32x4 bhi = *(const f32x4*)(bias + l5 * 8 + 4);
  float r0 = a0 * inv + blo.x;
  float r1 = a1 * inv + blo.y;
  float r2 = a2 * inv + blo.z;
  float r3 = a3 * inv + blo.w;
  float r4 = a4 * inv + bhi.x;
  float r5 = a5 * inv + bhi.y;
  float r6 = a6 * inv + bhi.z;
  float r7 = a7 * inv + bhi.w;
  r0 = r0 > 0.f ? r0 : __expf(r0) - 1.f;       // ELU (no libm)
  r1 = r1 > 0.f ? r1 : __expf(r1) - 1.f;
  r2 = r2 > 0.f ? r2 : __expf(r2) - 1.f;
  r3 = r3 > 0.f ? r3 : __expf(r3) - 1.f;
  r4 = r4 > 0.f ? r4 : __expf(r4) - 1.f;
  r5 = r5 > 0.f ? r5 : __expf(r5) - 1.f;
  r6 = r6 > 0.f ? r6 : __expf(r6) - 1.f;
  r7 = r7 > 0.f ? r7 : __expf(r7) - 1.f;
  f32x4 lo = {r0, r1, r2, r3};
  f32x4 hi = {r4, r5, r6, r7};
  f32x4 ov = half ? hi : lo;
  if (y == 0) {
    *(f32x4*)((char*)za + (size_t)n * 1024 + l5 * 32 + half * 16) = ov;
  } else {
    us4 o;
    o.x = f2b(ov.x); o.y = f2b(ov.y); o.z = f2b(ov.z); o.w = f2b(ov.w);
    *(us4*)((char*)zb + (size_t)n * 512 + l5 * 16 + half * 8) = o;
  }
}

// ---------------- semantic scores via MFMA (r14 passing version) -----------
__global__ __launch_bounds__(256)
void k_sem(const float* __restrict__ za,
           const unsigned short* __restrict__ zb,
           const unsigned short* __restrict__ w1t,
           const float* __restrict__ b1,
           const float* __restrict__ W2,
           float* __restrict__ wacc) {
  __shared__ us8 w1l[2048];                     // 64 rows x 32 chunks, 32KB
  __shared__ float psum[2];
  int t = threadIdx.x;
  int jbase = blockIdx.y * 64;                  // this block's j-half
  if (t < 2) psum[t] = 0.f;
  for (int i = t; i < 2048; i += 256) {
    int j = i >> 5, c = i & 31;                 // j local 0..63
    w1l[j * 32 + (c ^ (j & 7))] = ((const us8*)w1t)[(jbase + j) * 32 + c];
  }
  __syncthreads();
  int lane = t & 63, wave = t >> 6;
  int col = lane & 15, quad = lane >> 4;
  float b1v[4], w2v[4];
#pragma unroll
  for (int tt = 0; tt < 4; ++tt) {
    b1v[tt] = b1[jbase + tt * 16 + col];
    w2v[tt] = W2[jbase + tt * 16 + col];
  }
  int gt = blockIdx.x * 4 + wave;               // one tile per wave
  bool valid = gt < 6250;
  // load all 8 A fragments upfront (single latency exposure)
  bf16x8 afr[8];
  if (valid && gt < 3125) {
    const float* ap = za + (size_t)gt * 4096 + col * 256 + quad * 8;
#pragma unroll
    for (int ks = 0; ks < 8; ++ks) {
      f32x4 a0 = *(const f32x4*)(ap + ks * 32);
      f32x4 a1 = *(const f32x4*)(ap + ks * 32 + 4);
      afr[ks][0] = (short)f2b(a0.x); afr[ks][1] = (short)f2b(a0.y);
      afr[ks][2] = (short)f2b(a0.z); afr[ks][3] = (short)f2b(a0.w);
      afr[ks][4] = (short)f2b(a1.x); afr[ks][5] = (short)f2b(a1.y);
      afr[ks][6] = (short)f2b(a1.z); afr[ks][7] = (short)f2b(a1.w);
    }
  } else if (valid) {
    const unsigned short* ap = zb + (size_t)(gt - 3125) * 4096 + col * 256 +
                               quad * 8;
#pragma unroll
    for (int ks = 0; ks < 8; ++ks)
      afr[ks] = *(const bf16x8*)(ap + ks * 32);
  } else {
#pragma unroll
    for (int ks = 0; ks < 8; ++ks) afr[ks] = (bf16x8)(short)0;
  }
  f32x4 acc[4];
#pragma unroll
  for (int tt = 0; tt < 4; ++tt) acc[tt] = (f32x4){0.f, 0.f, 0.f, 0.f};
#pragma unroll
  for (int ks = 0; ks < 8; ++ks) {
    int c = ks * 4 + quad;
#pragma unroll
    for (int tt = 0; tt < 4; ++tt) {
      int j = tt * 16 + col;                    // local j
      bf16x8 b = (bf16x8)w1l[j * 32 + (c ^ (j & 7))];
      acc[tt] = __builtin_amdgcn_mfma_f32_16x16x32_bf16(afr[ks], b, acc[tt],
                                                        0, 0, 0);
    }
  }
  float tot = 0.f;
#pragma unroll
  for (int tt = 0; tt < 4; ++tt)
#pragma unroll
    for (int r = 0; r < 4; ++r) {
      float x = acc[tt][r] + b1v[tt];
      x = fminf(fmaxf(x, -10.f), 10.f);         // clamp for exp overflow
      float ex = __expf(2.f * x);               // tanh = (e^2x-1)/(e^2x+1)
      tot += (ex - 1.f) * __builtin_amdgcn_rcpf(ex + 1.f) * w2v[tt];
    }
#pragma unroll
  for (int off = 1; off < 64; off <<= 1) tot += __shfl_xor(tot, off);
  if (lane == 0 && valid)
    atomicAdd(&psum[gt < 3125 ? 0 : 1], tot);   // LDS atomic, cheap
  __syncthreads();
  if (t == 0 && psum[0] != 0.f) atomicAdd(&wacc[0], psum[0]);
  if (t == 1 && psum[1] != 0.f) atomicAdd(&wacc[1], psum[1]);
}

// ---------------- beta softmax + combine (in-place over za==out) -----------
__global__ __launch_bounds__(256)
void k_combine(const float* __restrict__ za,
               const unsigned short* __restrict__ zb,
               const float* __restrict__ wacc,
               float* __restrict__ out) {
  int i = blockIdx.x * 256 + threadIdx.x;       // 3.2M groups of 4
  float wa = wacc[0] * (1.f / kN), wb = wacc[1] * (1.f / kN);
  float mx = fmaxf(wa, wb);
  float ea = __expf(wa - mx), eb = __expf(wb - mx);
  float inv = __builtin_amdgcn_rcpf(ea + eb);
  float ba = ea * inv, bb = eb * inv;
  f32x4 x = ((const f32x4*)za)[i];
  us4 yv = ((const us4*)zb)[i];
  f32x4 o;
#pragma unroll
  for (int j = 0; j < 4; ++j)
    o[j] = ba * x[j] + bb * b2f(yv[j]);
  ((f32x4*)out)[i] = o;
}

extern "C" void kernel_launch(void* const* d_in, const int* in_sizes, int n_in,
                              void* d_out, int out_size, void* d_ws, size_t ws_size,
                              hipStream_t stream) {
  const float* hin = (const float*)d_in[0];
  const int* src_a = (const int*)d_in[1];
  const int* dst_a = (const int*)d_in[2];
  const int* src_b = (const int*)d_in[3];
  const int* dst_b = (const int*)d_in[4];
  const float* W_a = (const float*)d_in[5];
  const float* al_a = (const float*)d_in[6];
  const float* ar_a = (const float*)d_in[7];
  const float* bias_a = (const float*)d_in[8];
  const float* W_b = (const float*)d_in[9];
  const float* al_b = (const float*)d_in[10];
  const float* ar_b = (const float*)d_in[11];
  const float* bias_b = (const float*)d_in[12];
  const float* sW1 = (const float*)d_in[13];
  const float* sb1 = (const float*)d_in[14];
  const float* sW2 = (const float*)d_in[15];
  float* out = (float*)d_out;

  char* wsb = (char*)d_ws;
  size_t off = 0;
  auto alloc = [&](size_t bytes) -> char* {
    char* p = wsb + off;
    off = (off + bytes + 511) & ~(size_t)511;
    return p;
  };
  // Footprint ~98 MB.
  unsigned short* feat_a = (unsigned short*)alloc((size_t)kN * 256 * 2); // 25.6MB
  unsigned short* feat_b = (unsigned short*)alloc((size_t)kN * 256 * 2); // 25.6MB
  unsigned short* z_b    = (unsigned short*)alloc((size_t)kN * 256 * 2); // 25.6MB
  float* el_a = (float*)alloc((size_t)kN * 8 * 4);
  float* er_a = (float*)alloc((size_t)kN * 8 * 4);
  float* el_b = (float*)alloc((size_t)kN * 8 * 4);
  float* er_b = (float*)alloc((size_t)kN * 8 * 4);
  unsigned short* wt_a = (unsigned short*)alloc(65536 * 2);
  unsigned short* wt_b = (unsigned short*)alloc(65536 * 2);
  unsigned short* w1t  = (unsigned short*)alloc(32768 * 2);
  int* rp_a = (int*)alloc((size_t)(kN + 1) * 4);
  int* rp_b = (int*)alloc((size_t)(kN + 1) * 4);
  int* es_a = (int*)alloc((size_t)kE * 4);
  int* es_b = (int*)alloc((size_t)kE * 4);
  unsigned* pay = (unsigned*)alloc((size_t)2 * kNBUK * kCAP * 4);  // 7.2MB
  int* cnt = (int*)alloc((size_t)2 * kNBUK * 4);
  int* bbase = (int*)alloc((size_t)2 * kNBUK * 4);
  float* wacc = (float*)alloc(2 * 4);

  hipMemsetAsync(cnt, 0, (size_t)2 * kNBUK * 4, stream);
  hipMemsetAsync(wacc, 0, 8, stream);

  k_prep<<<640, 256, 0, stream>>>(W_a, W_b, sW1, wt_a, wt_b, w1t);
  k_part<<<dim3(125, 2), 256, 0, stream>>>(src_a, dst_a, src_b, dst_b, cnt, pay);
  k_bscan<<<1, 256, 0, stream>>>(cnt, bbase, rp_a, rp_b);
  k_bucket<<<dim3(kNBUK, 2), 256, 0, stream>>>(cnt, bbase, pay,
                                               rp_a, rp_b, es_a, es_b);
  k_gemm<<<dim3(782, 2), 512, 0, stream>>>(hin, wt_a, wt_b,
                                           al_a, ar_a, al_b, ar_b,
                                           feat_a, feat_b,
                                           el_a, er_a, el_b, er_b);
  k_agg<<<25000, 256, 0, stream>>>(rp_a, rp_b, es_a, es_b,
                                   el_a, er_a, el_b, er_b,
                                   feat_a, feat_b, bias_a, bias_b,
                                   out, z_b);
  k_sem<<<dim3(1563, 2), 256, 0, stream>>>(out, z_b, w1t, sb1, sW2, wacc);
  k_combine<<<12500, 256, 0, stream>>>(out, z_b, wacc, out);
}